// Round 4
// baseline (755.959 us; speedup 1.0000x reference)
//
#include <hip/hip_runtime.h>

typedef unsigned short u16;
typedef unsigned int   u32;
typedef __attribute__((ext_vector_type(8))) short short8;   // 8 x bf16
typedef __attribute__((ext_vector_type(4))) float f32x4;

__device__ __forceinline__ float b2f(u16 u) {
  union { float f; u32 i; } v; v.i = ((u32)u) << 16; return v.f;
}
__device__ __forceinline__ u16 f2b(float f) {
  union { float f; u32 i; } v; v.f = f;
  u32 r = v.i + 0x7fffu + ((v.i >> 16) & 1u);   // RNE
  return (u16)(r >> 16);
}

__device__ __forceinline__ void gload_lds16(const void* g, void* l) {
  __builtin_amdgcn_global_load_lds(
      (const __attribute__((address_space(1))) void*)g,
      (__attribute__((address_space(3))) void*)l, 16, 0, 0);
}

template <int N> __device__ __forceinline__ void wait_vmcnt() {
  if constexpr (N == 0)       asm volatile("s_waitcnt vmcnt(0)" ::: "memory");
  else if constexpr (N == 2)  asm volatile("s_waitcnt vmcnt(2)" ::: "memory");
  else if constexpr (N == 4)  asm volatile("s_waitcnt vmcnt(4)" ::: "memory");
  else if constexpr (N == 6)  asm volatile("s_waitcnt vmcnt(6)" ::: "memory");
  else if constexpr (N == 8)  asm volatile("s_waitcnt vmcnt(8)" ::: "memory");
  else if constexpr (N == 12) asm volatile("s_waitcnt vmcnt(12)" ::: "memory");
  else static_assert(N < 0, "unsupported vmcnt literal");
}

// ---------------- f32 -> bf16 convert (hidden states only) ----------------
__global__ __launch_bounds__(256) void cvt_bf16(const float* __restrict__ in,
                                                u16* __restrict__ out, int n4) {
  for (long i = (long)blockIdx.x * 256 + threadIdx.x; i < n4; i += (long)gridDim.x * 256) {
    const float4 v = ((const float4*)in)[i];
    ushort4 o;
    o.x = f2b(v.x); o.y = f2b(v.y); o.z = f2b(v.z); o.w = f2b(v.w);
    ((ushort4*)out)[i] = o;
  }
}

__device__ __forceinline__ short8 frag_ld(const u16* base, int rbase, int fr, int fq) {
  const int r = rbase + fr;
  return *(const short8*)(base + r * 32 + ((fq ^ ((r >> 1) & 3)) << 3));
}

// ---------------- GEMM: C(MxN) = A(MxK,bf16) * B(NxK,f32)^T ----------------
// Per-wave 128x64. Ring-3 LDS slots; ONE barrier per K-step (slots t, t+1,
// t+2 are distinct mod 3 for read/B-write/A-stage -> no intra-iter barrier
// needed). A: global_load_lds 2 tiles ahead. B: f32 reg-staged 2 tiles ahead
// (brE/brO, static parity indexing), converted+ds_written 1 tile ahead (T14).
// Counted vmcnt only (T4): never drains mid-loop. Requires NT=K/32 even, >=4.
#define MF(m_, n_) acc[m_][n_] = __builtin_amdgcn_mfma_f32_16x16x32_bf16(a##m_, b##n_, acc[m_][n_], 0, 0, 0);

#define GEMM_FB_ITER(T_, BRI, BRC)                                            \
  {                                                                            \
    const u16* SA = lds + ((T_) % 3) * SLOT;                                   \
    const u16* SB = SA + AE;                                                   \
    short8 a0 = frag_ld(SA, mA +  0, fr, fq);                                  \
    short8 a1 = frag_ld(SA, mA + 16, fr, fq);                                  \
    short8 a2 = frag_ld(SA, mA + 32, fr, fq);                                  \
    short8 a3 = frag_ld(SA, mA + 48, fr, fq);                                  \
    short8 b0 = frag_ld(SB, nB +  0, fr, fq);                                  \
    short8 b1 = frag_ld(SB, nB + 16, fr, fq);                                  \
    short8 b2 = frag_ld(SB, nB + 32, fr, fq);                                  \
    short8 b3 = frag_ld(SB, nB + 48, fr, fq);                                  \
    if ((T_) + 2 < NT) {                                                       \
      const long kb = (long)((T_) + 2) * 32;                                   \
      _Pragma("unroll") for (int i = 0; i < LPT_B; ++i) {                      \
        BRI[i][0] = *(const float4*)(Bsrc[i] + kb);                            \
        BRI[i][1] = *(const float4*)(Bsrc[i] + kb + 4);                        \
      }                                                                        \
      __builtin_amdgcn_sched_barrier(0);                                       \
      u16* SD = lds + (((T_) + 2) % 3) * SLOT;                                 \
      _Pragma("unroll") for (int i = 0; i < LPT_A; ++i)                        \
        gload_lds16(gA[i] + ((T_) + 2) * 32, SD + dA[i]);                      \
      __builtin_amdgcn_sched_barrier(0);                                       \
    }                                                                          \
    __builtin_amdgcn_s_setprio(1);                                             \
    MF(0,0) MF(0,1) MF(0,2) MF(0,3)                                            \
    MF(1,0) MF(1,1) MF(1,2) MF(1,3)                                            \
    MF(2,0) MF(2,1) MF(2,2) MF(2,3)                                            \
    MF(3,0) MF(3,1) MF(3,2) MF(3,3)                                            \
    __builtin_amdgcn_s_setprio(0);                                             \
    short8 a4 = frag_ld(SA, mA +  64, fr, fq);                                 \
    short8 a5 = frag_ld(SA, mA +  80, fr, fq);                                 \
    short8 a6 = frag_ld(SA, mA +  96, fr, fq);                                 \
    short8 a7 = frag_ld(SA, mA + 112, fr, fq);                                 \
    if ((T_) + 1 < NT) {                                                       \
      if ((T_) + 2 < NT) wait_vmcnt<2 * NA_V + NB_V>();                        \
      else               wait_vmcnt<NA_V>();                                   \
      u16* wd = lds + (((T_) + 1) % 3) * SLOT;                                 \
      _Pragma("unroll") for (int i = 0; i < LPT_B; ++i) {                      \
        short8 v;                                                              \
        v[0] = (short)f2b(BRC[i][0].x); v[1] = (short)f2b(BRC[i][0].y);        \
        v[2] = (short)f2b(BRC[i][0].z); v[3] = (short)f2b(BRC[i][0].w);        \
        v[4] = (short)f2b(BRC[i][1].x); v[5] = (short)f2b(BRC[i][1].y);        \
        v[6] = (short)f2b(BRC[i][1].z); v[7] = (short)f2b(BRC[i][1].w);        \
        *(short8*)(wd + dB[i]) = v;                                            \
      }                                                                        \
    }                                                                          \
    __builtin_amdgcn_s_setprio(1);                                             \
    MF(4,0) MF(4,1) MF(4,2) MF(4,3)                                            \
    MF(5,0) MF(5,1) MF(5,2) MF(5,3)                                            \
    MF(6,0) MF(6,1) MF(6,2) MF(6,3)                                            \
    MF(7,0) MF(7,1) MF(7,2) MF(7,3)                                            \
    __builtin_amdgcn_s_setprio(0);                                             \
    if ((T_) + 2 < NT) wait_vmcnt<NA_V + NB_V>();                              \
    else               wait_vmcnt<0>();                                        \
    asm volatile("s_waitcnt lgkmcnt(0)" ::: "memory");                         \
    __builtin_amdgcn_s_barrier();                                              \
  }

template <int NWM, int NWN, typename OutT>
__global__ __launch_bounds__(NWM * NWN * 64, 2) void gemm_fb(
    const u16* __restrict__ A, const float* __restrict__ Bf,
    OutT* __restrict__ C, int M, int N, int K) {
  constexpr int NTHR = NWM * NWN * 64;
  constexpr int BM = NWM * 128, BN = NWN * 64;
  constexpr int AE = BM * 32, SLOT = AE + BN * 32;     // u16 counts
  constexpr int LPT_A = (BM * 4) / NTHR;               // 16B chunks / thread
  constexpr int LPT_B = (BN * 4) / NTHR;
  constexpr int NA_V = LPT_A;                          // VMEM ops per A tile
  constexpr int NB_V = LPT_B * 2;                      // VMEM ops per B tile
  __shared__ u16 lds[3 * SLOT];
  const int tid = threadIdx.x;
  const int wid = tid >> 6, lane = tid & 63;
  const int fr = lane & 15, fq = lane >> 4;
  const int mA = (wid / NWN) * 128, nB = (wid % NWN) * 64;

  // XCD-chunked column-major tile mapping (grid % 8 == 0)
  const int nty = M / BM;
  const int qx = gridDim.x >> 3;
  const int wg = (blockIdx.x & 7) * qx + (blockIdx.x >> 3);
  const int by = wg % nty, bx = wg / nty;
  const long row0 = (long)by * BM, col0 = (long)bx * BN;

  const u16* gA[LPT_A];
  int dA[LPT_A];
#pragma unroll
  for (int i = 0; i < LPT_A; ++i) {
    const int c = tid + i * NTHR, r = c >> 2, j = (c & 3) ^ ((r >> 1) & 3);
    gA[i] = A + (row0 + r) * (long)K + j * 8;
    dA[i] = c * 8;
  }
  const float* Bsrc[LPT_B];
  int dB[LPT_B];
#pragma unroll
  for (int i = 0; i < LPT_B; ++i) {
    const int c = tid + i * NTHR, r = c >> 2, j = (c & 3) ^ ((r >> 1) & 3);
    Bsrc[i] = Bf + (col0 + r) * (long)K + j * 8;
    dB[i] = AE + c * 8;
  }

  f32x4 acc[8][4];
#pragma unroll
  for (int m = 0; m < 8; ++m)
#pragma unroll
    for (int n = 0; n < 4; ++n) acc[m][n] = f32x4{0.f, 0.f, 0.f, 0.f};

  const int NT = K >> 5;        // even, >= 4
  float4 brE[LPT_B][2], brO[LPT_B][2];

  // prologue — FIFO: [A0, B0, B1, A1]; wait leaves B1+A1 in flight
#pragma unroll
  for (int i = 0; i < LPT_A; ++i) gload_lds16(gA[i], lds + dA[i]);
  __builtin_amdgcn_sched_barrier(0);
#pragma unroll
  for (int i = 0; i < LPT_B; ++i) {
    brE[i][0] = *(const float4*)(Bsrc[i]);
    brE[i][1] = *(const float4*)(Bsrc[i] + 4);
  }
#pragma unroll
  for (int i = 0; i < LPT_B; ++i) {
    brO[i][0] = *(const float4*)(Bsrc[i] + 32);
    brO[i][1] = *(const float4*)(Bsrc[i] + 36);
  }
  __builtin_amdgcn_sched_barrier(0);
#pragma unroll
  for (int i = 0; i < LPT_A; ++i) gload_lds16(gA[i] + 32, lds + SLOT + dA[i]);
  __builtin_amdgcn_sched_barrier(0);
  wait_vmcnt<NA_V + NB_V>();    // A0,B0 done; B1,A1 in flight
#pragma unroll
  for (int i = 0; i < LPT_B; ++i) {
    short8 v;
    v[0] = (short)f2b(brE[i][0].x); v[1] = (short)f2b(brE[i][0].y);
    v[2] = (short)f2b(brE[i][0].z); v[3] = (short)f2b(brE[i][0].w);
    v[4] = (short)f2b(brE[i][1].x); v[5] = (short)f2b(brE[i][1].y);
    v[6] = (short)f2b(brE[i][1].z); v[7] = (short)f2b(brE[i][1].w);
    *(short8*)(lds + dB[i]) = v;
  }
  asm volatile("s_waitcnt lgkmcnt(0)" ::: "memory");
  __builtin_amdgcn_s_barrier();

  for (int t = 0; t < NT; t += 2) {
    GEMM_FB_ITER(t, brE, brO)          // issues even tile t+2, converts odd t+1
    GEMM_FB_ITER(t + 1, brO, brE)      // issues odd tile t+3, converts even t+2
  }

#pragma unroll
  for (int m = 0; m < 8; ++m)
#pragma unroll
    for (int n = 0; n < 4; ++n)
#pragma unroll
      for (int j = 0; j < 4; ++j) {
        const long r = row0 + mA + m * 16 + fq * 4 + j;
        const long c = col0 + nB + n * 16 + fr;
        if constexpr (sizeof(OutT) == 2) C[r * N + c] = f2b(acc[m][n][j]);
        else                             C[r * N + c] = acc[m][n][j];
      }
}

// ---------------- RoPE in-place on q,k (cols 0..8191 of qkv) ----------------
__global__ __launch_bounds__(256) void rope_qk(u16* __restrict__ qkv,
                                               const float* __restrict__ cosb,
                                               const float* __restrict__ sinb) {
  const int s = blockIdx.x;
  __shared__ u16 row[8192];
  const uint4* src = (const uint4*)(qkv + (long)s * 12288);
  uint4* dst = (uint4*)row;
  for (int i = threadIdx.x; i < 1024; i += 256) dst[i] = src[i];
  __syncthreads();
  const float scale = 0.08838834764831845f;  // 1/sqrt(128)
  for (int i = threadIdx.x; i < 8192; i += 256) {
    const int d = i & 127;
    const int base = i & ~127;
    const float x  = b2f(row[i]);
    const float x2 = b2f(row[base + ((d + 64) & 127)]);
    const float c  = cosb[s * 128 + d];
    const float sn = sinb[s * 128 + d];
    float v = x * c + ((d < 64) ? -x2 : x2) * sn;
    if (i < 4096) v *= scale;                // q only
    qkv[(long)s * 12288 + i] = f2b(v);
  }
}

// ---------------- transpose V: qkv[:,8192+f] (S x 4096) -> vt (4096 x S) ----
__global__ __launch_bounds__(256) void transpose_v(const u16* __restrict__ qkv,
                                                   u16* __restrict__ vt) {
  __shared__ u16 tile[64][72];
  const int f0 = blockIdx.x * 64;
  const int s0 = blockIdx.y * 64;
  const int tid = threadIdx.x;
  const int rr = tid >> 3;
  const int cc = (tid & 7) * 8;
#pragma unroll
  for (int p = 0; p < 2; ++p) {
    const int sr = p * 32 + rr;
    *(uint4*)&tile[sr][cc] =
        *(const uint4*)(qkv + (long)(s0 + sr) * 12288 + 8192 + f0 + cc);
  }
  __syncthreads();
#pragma unroll
  for (int p = 0; p < 2; ++p) {
    const int fr = p * 32 + rr;
    u16 tmp[8];
#pragma unroll
    for (int j = 0; j < 8; ++j) tmp[j] = tile[cc + j][fr];
    *(uint4*)(vt + (long)(f0 + fr) * 2048 + s0 + cc) = *(uint4*)tmp;
  }
}

// ---------------- causal flash attention ------------------------------------
__global__ __launch_bounds__(256) void attn_fwd(const u16* __restrict__ Qb,
                                                const u16* __restrict__ Kb,
                                                const u16* __restrict__ Vt,
                                                u16* __restrict__ Ob) {
  const int h  = blockIdx.y;
  const int q0 = blockIdx.x * 64;
  const int tid = threadIdx.x;
  const int wid = tid >> 6, lane = tid & 63;
  const int fr = lane & 15, fq = lane >> 4;

  __shared__ u16 Ks[64 * 128];
  __shared__ u16 Vts[128 * 64];
  __shared__ u16 Ps[4][16 * 72];

  short8 qf[4];
  {
    const long qrow = q0 + wid * 16 + fr;
#pragma unroll
    for (int kk = 0; kk < 4; ++kk)
      qf[kk] = *(const short8*)(Qb + qrow * 12288 + h * 128 + kk * 32 + fq * 8);
  }

  f32x4 Oacc[8];
#pragma unroll
  for (int f = 0; f < 8; ++f) Oacc[f] = f32x4{0.f, 0.f, 0.f, 0.f};
  float mrun[4], lrun[4];
#pragma unroll
  for (int j = 0; j < 4; ++j) { mrun[j] = -1e30f; lrun[j] = 0.f; }

  const int nt = blockIdx.x + 1;
  for (int t = 0; t < nt; ++t) {
    const int kv0 = t * 64;
#pragma unroll
    for (int i = 0; i < 4; ++i) {
      const int c = wid * 4 + i;
      {
        const int r = c * 4 + (lane >> 4);
        const int p = lane & 15;
        const int jsrc = p ^ (r & 7);
        gload_lds16(Kb + (long)(kv0 + r) * 12288 + h * 128 + jsrc * 8,
                    (char*)Ks + c * 1024);
      }
      {
        const int d = c * 8 + (lane >> 3);
        const int p = lane & 7;
        const int jsrc = p ^ (d & 7);
        gload_lds16(Vt + (long)(h * 128 + d) * 2048 + kv0 + jsrc * 8,
                    (char*)Vts + c * 1024);
      }
    }
    __syncthreads();

    f32x4 S[4];
#pragma unroll
    for (int n = 0; n < 4; ++n) S[n] = f32x4{0.f, 0.f, 0.f, 0.f};
#pragma unroll
    for (int kk = 0; kk < 4; ++kk) {
#pragma unroll
      for (int n = 0; n < 4; ++n) {
        const int r = n * 16 + fr;
        const int p = (kk * 4 + fq) ^ (r & 7);
        short8 kf = *(const short8*)((const char*)Ks + r * 256 + p * 16);
        S[n] = __builtin_amdgcn_mfma_f32_16x16x32_bf16(qf[kk], kf, S[n], 0, 0, 0);
      }
    }

    float P[4][4];
    float tm[4] = {-1e30f, -1e30f, -1e30f, -1e30f};
#pragma unroll
    for (int n = 0; n < 4; ++n) {
      const int kv = kv0 + n * 16 + fr;
#pragma unroll
      for (int j = 0; j < 4; ++j) {
        const int qi = q0 + wid * 16 + fq * 4 + j;
        const float s = (kv <= qi) ? S[n][j] : -1e30f;
        P[n][j] = s;
        tm[j] = fmaxf(tm[j], s);
      }
    }
#pragma unroll
    for (int j = 0; j < 4; ++j)
#pragma unroll
      for (int msk = 1; msk < 16; msk <<= 1)
        tm[j] = fmaxf(tm[j], __shfl_xor(tm[j], msk));

    float al[4], rs[4];
#pragma unroll
    for (int j = 0; j < 4; ++j) {
      const float mn = fmaxf(mrun[j], tm[j]);
      al[j] = __expf(mrun[j] - mn);
      mrun[j] = mn;
      rs[j] = 0.f;
    }
#pragma unroll
    for (int n = 0; n < 4; ++n)
#pragma unroll
      for (int j = 0; j < 4; ++j) {
        const float p = __expf(P[n][j] - mrun[j]);
        P[n][j] = p;
        rs[j] += p;
      }
#pragma unroll
    for (int j = 0; j < 4; ++j) {
#pragma unroll
      for (int msk = 1; msk < 16; msk <<= 1) rs[j] += __shfl_xor(rs[j], msk);
      lrun[j] = lrun[j] * al[j] + rs[j];
    }
#pragma unroll
    for (int f = 0; f < 8; ++f) {
      f32x4 o = Oacc[f];
#pragma unroll
      for (int j = 0; j < 4; ++j) o[j] *= al[j];
      Oacc[f] = o;
    }

#pragma unroll
    for (int n = 0; n < 4; ++n)
#pragma unroll
      for (int j = 0; j < 4; ++j)
        Ps[wid][(fq * 4 + j) * 72 + n * 16 + fr] = f2b(P[n][j]);

#pragma unroll
    for (int kb = 0; kb < 2; ++kb) {
      short8 pa = *(const short8*)(Ps[wid] + fr * 72 + kb * 32 + fq * 8);
#pragma unroll
      for (int f = 0; f < 8; ++f) {
        const int d = f * 16 + fr;
        const int p = (kb * 4 + fq) ^ (d & 7);
        short8 vf = *(const short8*)((const char*)Vts + d * 128 + p * 16);
        Oacc[f] = __builtin_amdgcn_mfma_f32_16x16x32_bf16(pa, vf, Oacc[f], 0, 0, 0);
      }
    }
    __syncthreads();
  }

#pragma unroll
  for (int j = 0; j < 4; ++j) {
    const float inv = 1.f / lrun[j];
    const long r = q0 + wid * 16 + fq * 4 + j;
#pragma unroll
    for (int f = 0; f < 8; ++f)
      Ob[r * 4096 + h * 128 + f * 16 + fr] = f2b(Oacc[f][j] * inv);
  }
}

// ---------------- launch ----------------------------------------------------
extern "C" void kernel_launch(void* const* d_in, const int* in_sizes, int n_in,
                              void* d_out, int out_size, void* d_ws, size_t ws_size,
                              hipStream_t stream) {
  const float* hs   = (const float*)d_in[0];   // (2048, 4096)
  const float* cosb = (const float*)d_in[1];   // (2048, 128)
  const float* sinb = (const float*)d_in[2];   // (2048, 128)
  const float* wp   = (const float*)d_in[3];   // (12288, 4096)
  const float* wo   = (const float*)d_in[4];   // (4096, 4096)
  float* out = (float*)d_out;                  // (2048, 4096)
  char* ws = (char*)d_ws;

  // workspace: h_bf 16MB | qkv 48MB | vt 16MB | attn 16MB  (total 96MB)
  u16* h_bf = (u16*)(ws);
  u16* qkv  = (u16*)(ws + 16777216);
  u16* vt   = (u16*)(ws + 67108864);
  u16* attn = (u16*)(ws + 83886080);

  cvt_bf16<<<2048, 256, 0, stream>>>(hs, h_bf, 8388608 / 4);
  gemm_fb<2, 4, u16><<<384, 512, 0, stream>>>(h_bf, wp, qkv, 2048, 12288, 4096);
  rope_qk<<<2048, 256, 0, stream>>>(qkv, cosb, sinb);
  transpose_v<<<dim3(64, 32), 256, 0, stream>>>(qkv, vt);
  attn_fwd<<<dim3(32, 32), 256, 0, stream>>>(qkv, qkv + 4096, vt, attn);
  gemm_fb<2, 2, float><<<256, 256, 0, stream>>>(attn, wo, out, 2048, 4096, 4096);
}

// Round 5
// 551.981 us; speedup vs baseline: 1.3695x; 1.3695x over previous
//
#include <hip/hip_runtime.h>

typedef unsigned short u16;
typedef unsigned int   u32;
typedef __attribute__((ext_vector_type(8))) short short8;   // 8 x bf16
typedef __attribute__((ext_vector_type(4))) float f32x4;

__device__ __forceinline__ float b2f(u16 u) {
  union { float f; u32 i; } v; v.i = ((u32)u) << 16; return v.f;
}
__device__ __forceinline__ u16 f2b(float f) {
  union { float f; u32 i; } v; v.f = f;
  u32 r = v.i + 0x7fffu + ((v.i >> 16) & 1u);   // RNE
  return (u16)(r >> 16);
}

__device__ __forceinline__ void gload_lds16(const void* g, void* l) {
  __builtin_amdgcn_global_load_lds(
      (const __attribute__((address_space(1))) void*)g,
      (__attribute__((address_space(3))) void*)l, 16, 0, 0);
}

// ---------------- f32 -> bf16 converts ----------------
__device__ __forceinline__ ushort4 cvt4(float4 v) {
  ushort4 o;
  o.x = f2b(v.x); o.y = f2b(v.y); o.z = f2b(v.z); o.w = f2b(v.w);
  return o;
}

__global__ __launch_bounds__(256) void cvt_hp(const float* __restrict__ hs,
                                              const float* __restrict__ wp,
                                              u16* __restrict__ h_bf,
                                              u16* __restrict__ wp_bf) {
  const long H4 = 2097152, W4 = 12582912;   // float4 counts
  for (long i = (long)blockIdx.x * 256 + threadIdx.x; i < H4 + W4;
       i += (long)gridDim.x * 256) {
    if (i < H4)
      ((ushort4*)h_bf)[i] = cvt4(((const float4*)hs)[i]);
    else
      ((ushort4*)wp_bf)[i - H4] = cvt4(((const float4*)wp)[i - H4]);
  }
}

__global__ __launch_bounds__(256) void cvt_bf16(const float* __restrict__ in,
                                                u16* __restrict__ out, int n4) {
  for (long i = (long)blockIdx.x * 256 + threadIdx.x; i < n4; i += (long)gridDim.x * 256)
    ((ushort4*)out)[i] = cvt4(((const float4*)in)[i]);
}

// ---------------- GEMM: C(MxN) = A(MxK) * B(NxK)^T, bf16 in ---------------
// R2-proven structure: 256x128 tile, BK=32, 8 waves (4M x 2N, 64x64/wave),
// ring-4 LDS (96 KiB), counted vmcnt(6/3/0), chunk-XOR swizzle, setprio,
// XCD-chunked column-major mapping. grid=(M/256)*(N/128), grid%8==0, K/32>=3.
// EPI 0: u16 C (qkv); blocks with col0>=8192 write transposed into VT instead.
// EPI 1: float C.
__device__ __forceinline__ short8 frag_ld(const u16* base, int rbase, int fr, int fq) {
  const int r = rbase + fr;
  return *(const short8*)(base + r * 32 + ((fq ^ ((r >> 1) & 3)) << 3));
}

template <int EPI>
__global__ __launch_bounds__(512, 2) void gemm256(const u16* __restrict__ A,
                                                  const u16* __restrict__ B,
                                                  void* __restrict__ Cv,
                                                  u16* __restrict__ VT,
                                                  int M, int N, int K) {
  __shared__ u16 lds[4 * 12288];          // 4 slots x (A 8192 + B 4096) u16
  const int tid = threadIdx.x;
  const int wid = tid >> 6, lane = tid & 63;
  const int fr = lane & 15, fq = lane >> 4;
  const int mA = (wid >> 1) * 64;         // wave row base within tile
  const int nB = (wid & 1) * 64;          // wave col base within tile

  // XCD-chunked column-major tile mapping (grid % 8 == 0)
  const int nty = M >> 8;                 // tiles along M (256)
  const int q = gridDim.x >> 3;
  const int wg = (blockIdx.x & 7) * q + (blockIdx.x >> 3);
  const int by = wg % nty;
  const int bx = wg / nty;
  const long row0 = (long)by * 256;
  const long col0 = (long)bx * 128;

  // staging: 3 x 16B chunks per thread per K-tile (A: 1024 chunks, B: 512)
  const int c0 = tid, c1 = 512 + tid, cB = tid;
  const int rA0 = c0 >> 2, j0 = (c0 & 3) ^ ((rA0 >> 1) & 3);
  const int rA1 = c1 >> 2, j1 = (c1 & 3) ^ ((rA1 >> 1) & 3);
  const int rB  = cB >> 2, j2 = (cB & 3) ^ ((rB >> 1) & 3);
  const u16* gA0 = A + (row0 + rA0) * (long)K + j0 * 8;
  const u16* gA1 = A + (row0 + rA1) * (long)K + j1 * 8;
  const u16* gB  = B + (col0 + rB) * (long)K + j2 * 8;
  const int dA0 = c0 * 8, dA1 = c1 * 8, dB = 8192 + cB * 8;

  f32x4 acc[4][4];
#pragma unroll
  for (int m = 0; m < 4; ++m)
#pragma unroll
    for (int n = 0; n < 4; ++n) acc[m][n] = f32x4{0.f, 0.f, 0.f, 0.f};

  const int NT = K >> 5;

  // prologue: stage tiles 0,1,2 into slots 0,1,2; wait tile 0 (2 in flight)
#pragma unroll
  for (int pt = 0; pt < 3; ++pt) {
    u16* s = lds + pt * 12288;
    gload_lds16(gA0 + pt * 32, s + dA0);
    gload_lds16(gA1 + pt * 32, s + dA1);
    gload_lds16(gB  + pt * 32, s + dB);
  }
  asm volatile("s_waitcnt vmcnt(6)" ::: "memory");
  __builtin_amdgcn_s_barrier();

  for (int t = 0; t < NT; ++t) {
    const u16* SA = lds + (t & 3) * 12288;
    const u16* SB = SA + 8192;
    u16* ST = lds + ((t + 3) & 3) * 12288;
    const bool st = (t + 3) < NT;
    const int sk = (t + 3) * 32;

    // ---- phase 1: frags m0,m1 + all B; stage 2 chunks; 8 MFMA ----
    short8 a0 = frag_ld(SA, mA +  0, fr, fq);
    short8 a1 = frag_ld(SA, mA + 16, fr, fq);
    short8 b0 = frag_ld(SB, nB +  0, fr, fq);
    short8 b1 = frag_ld(SB, nB + 16, fr, fq);
    short8 b2 = frag_ld(SB, nB + 32, fr, fq);
    short8 b3 = frag_ld(SB, nB + 48, fr, fq);
    if (st) {
      gload_lds16(gA0 + sk, ST + dA0);
      gload_lds16(gA1 + sk, ST + dA1);
    }
    __builtin_amdgcn_s_barrier();
    __builtin_amdgcn_s_setprio(1);
    acc[0][0] = __builtin_amdgcn_mfma_f32_16x16x32_bf16(a0, b0, acc[0][0], 0, 0, 0);
    acc[0][1] = __builtin_amdgcn_mfma_f32_16x16x32_bf16(a0, b1, acc[0][1], 0, 0, 0);
    acc[0][2] = __builtin_amdgcn_mfma_f32_16x16x32_bf16(a0, b2, acc[0][2], 0, 0, 0);
    acc[0][3] = __builtin_amdgcn_mfma_f32_16x16x32_bf16(a0, b3, acc[0][3], 0, 0, 0);
    acc[1][0] = __builtin_amdgcn_mfma_f32_16x16x32_bf16(a1, b0, acc[1][0], 0, 0, 0);
    acc[1][1] = __builtin_amdgcn_mfma_f32_16x16x32_bf16(a1, b1, acc[1][1], 0, 0, 0);
    acc[1][2] = __builtin_amdgcn_mfma_f32_16x16x32_bf16(a1, b2, acc[1][2], 0, 0, 0);
    acc[1][3] = __builtin_amdgcn_mfma_f32_16x16x32_bf16(a1, b3, acc[1][3], 0, 0, 0);
    __builtin_amdgcn_s_setprio(0);
    __builtin_amdgcn_s_barrier();

    // ---- phase 2: frags m2,m3 (reuse B); stage 1 chunk; 8 MFMA ----
    short8 a2 = frag_ld(SA, mA + 32, fr, fq);
    short8 a3 = frag_ld(SA, mA + 48, fr, fq);
    if (st) gload_lds16(gB + sk, ST + dB);
    __builtin_amdgcn_s_barrier();
    __builtin_amdgcn_s_setprio(1);
    acc[2][0] = __builtin_amdgcn_mfma_f32_16x16x32_bf16(a2, b0, acc[2][0], 0, 0, 0);
    acc[2][1] = __builtin_amdgcn_mfma_f32_16x16x32_bf16(a2, b1, acc[2][1], 0, 0, 0);
    acc[2][2] = __builtin_amdgcn_mfma_f32_16x16x32_bf16(a2, b2, acc[2][2], 0, 0, 0);
    acc[2][3] = __builtin_amdgcn_mfma_f32_16x16x32_bf16(a2, b3, acc[2][3], 0, 0, 0);
    acc[3][0] = __builtin_amdgcn_mfma_f32_16x16x32_bf16(a3, b0, acc[3][0], 0, 0, 0);
    acc[3][1] = __builtin_amdgcn_mfma_f32_16x16x32_bf16(a3, b1, acc[3][1], 0, 0, 0);
    acc[3][2] = __builtin_amdgcn_mfma_f32_16x16x32_bf16(a3, b2, acc[3][2], 0, 0, 0);
    acc[3][3] = __builtin_amdgcn_mfma_f32_16x16x32_bf16(a3, b3, acc[3][3], 0, 0, 0);
    __builtin_amdgcn_s_setprio(0);
    if (t + 3 < NT)      asm volatile("s_waitcnt vmcnt(6)" ::: "memory");
    else if (t + 2 < NT) asm volatile("s_waitcnt vmcnt(3)" ::: "memory");
    else                 asm volatile("s_waitcnt vmcnt(0)" ::: "memory");
    __builtin_amdgcn_s_barrier();
  }

  if constexpr (EPI == 0) {
    if (col0 >= 8192) {
      // V block: write transposed into VT (4096 x 2048)
#pragma unroll
      for (int m = 0; m < 4; ++m)
#pragma unroll
        for (int n = 0; n < 4; ++n) {
          const long vcol = col0 - 8192 + nB + n * 16 + fr;
          const long rbase = row0 + mA + m * 16 + fq * 4;
          ushort4 o;
          o.x = f2b(acc[m][n][0]); o.y = f2b(acc[m][n][1]);
          o.z = f2b(acc[m][n][2]); o.w = f2b(acc[m][n][3]);
          *(ushort4*)(VT + vcol * 2048 + rbase) = o;
        }
    } else {
      u16* C = (u16*)Cv;
#pragma unroll
      for (int m = 0; m < 4; ++m)
#pragma unroll
        for (int n = 0; n < 4; ++n)
#pragma unroll
          for (int j = 0; j < 4; ++j) {
            const long r = row0 + mA + m * 16 + fq * 4 + j;
            const long c = col0 + nB + n * 16 + fr;
            C[r * N + c] = f2b(acc[m][n][j]);
          }
    }
  } else {
    float* C = (float*)Cv;
#pragma unroll
    for (int m = 0; m < 4; ++m)
#pragma unroll
      for (int n = 0; n < 4; ++n)
#pragma unroll
        for (int j = 0; j < 4; ++j) {
          const long r = row0 + mA + m * 16 + fq * 4 + j;
          const long c = col0 + nB + n * 16 + fr;
          C[r * N + c] = acc[m][n][j];
        }
  }
}

// ---------------- RoPE on q,k (vectorized, out-of-LDS) ---------------------
// thread <-> (s, seg, h, dq): computes both halves of a (d, d+64) pair block.
// out[d]    = x[d]*cos[d]   - x[d+64]*sin[d]      (d < 64)
// out[d+64] = x[d+64]*cos[d+64] + x[d]*sin[d+64]
__global__ __launch_bounds__(256) void rope_qk(u16* __restrict__ qkv,
                                               const float* __restrict__ cosb,
                                               const float* __restrict__ sinb) {
  const int idx = blockIdx.x * 256 + threadIdx.x;   // grid exact: 2,097,152
  const int dq  = idx & 15;
  const int h   = (idx >> 4) & 31;
  const int seg = (idx >> 9) & 1;                   // 0 = q, 1 = k
  const int s   = idx >> 10;
  const int d0  = dq * 4;
  u16* base = qkv + (long)s * 12288 + seg * 4096 + h * 128;
  const ushort4 x1 = *(const ushort4*)(base + d0);
  const ushort4 x2 = *(const ushort4*)(base + d0 + 64);
  const float4 c1 = *(const float4*)(cosb + s * 128 + d0);
  const float4 s1 = *(const float4*)(sinb + s * 128 + d0);
  const float4 c2 = *(const float4*)(cosb + s * 128 + d0 + 64);
  const float4 s2 = *(const float4*)(sinb + s * 128 + d0 + 64);
  const float scale = seg ? 1.0f : 0.08838834764831845f;   // 1/sqrt(128) on q
  float x1f[4] = {b2f(x1.x), b2f(x1.y), b2f(x1.z), b2f(x1.w)};
  float x2f[4] = {b2f(x2.x), b2f(x2.y), b2f(x2.z), b2f(x2.w)};
  const float c1a[4] = {c1.x, c1.y, c1.z, c1.w}, s1a[4] = {s1.x, s1.y, s1.z, s1.w};
  const float c2a[4] = {c2.x, c2.y, c2.z, c2.w}, s2a[4] = {s2.x, s2.y, s2.z, s2.w};
  ushort4 o1, o2;
  u16* o1p = (u16*)&o1; u16* o2p = (u16*)&o2;
#pragma unroll
  for (int j = 0; j < 4; ++j) {
    o1p[j] = f2b((x1f[j] * c1a[j] - x2f[j] * s1a[j]) * scale);
    o2p[j] = f2b((x2f[j] * c2a[j] + x1f[j] * s2a[j]) * scale);
  }
  *(ushort4*)(base + d0) = o1;
  *(ushort4*)(base + d0 + 64) = o2;
}

// ---------------- causal flash attention ------------------------------------
__global__ __launch_bounds__(256) void attn_fwd(const u16* __restrict__ Qb,
                                                const u16* __restrict__ Kb,
                                                const u16* __restrict__ Vt,
                                                u16* __restrict__ Ob) {
  const int h  = blockIdx.y;
  const int q0 = blockIdx.x * 64;
  const int tid = threadIdx.x;
  const int wid = tid >> 6, lane = tid & 63;
  const int fr = lane & 15, fq = lane >> 4;

  __shared__ u16 Ks[64 * 128];
  __shared__ u16 Vts[128 * 64];
  __shared__ u16 Ps[4][16 * 72];

  short8 qf[4];
  {
    const long qrow = q0 + wid * 16 + fr;
#pragma unroll
    for (int kk = 0; kk < 4; ++kk)
      qf[kk] = *(const short8*)(Qb + qrow * 12288 + h * 128 + kk * 32 + fq * 8);
  }

  f32x4 Oacc[8];
#pragma unroll
  for (int f = 0; f < 8; ++f) Oacc[f] = f32x4{0.f, 0.f, 0.f, 0.f};
  float mrun[4], lrun[4];
#pragma unroll
  for (int j = 0; j < 4; ++j) { mrun[j] = -1e30f; lrun[j] = 0.f; }

  const int nt = blockIdx.x + 1;
  for (int t = 0; t < nt; ++t) {
    const int kv0 = t * 64;
#pragma unroll
    for (int i = 0; i < 4; ++i) {
      const int c = wid * 4 + i;
      {
        const int r = c * 4 + (lane >> 4);
        const int p = lane & 15;
        const int jsrc = p ^ (r & 7);
        gload_lds16(Kb + (long)(kv0 + r) * 12288 + h * 128 + jsrc * 8,
                    (char*)Ks + c * 1024);
      }
      {
        const int d = c * 8 + (lane >> 3);
        const int p = lane & 7;
        const int jsrc = p ^ (d & 7);
        gload_lds16(Vt + (long)(h * 128 + d) * 2048 + kv0 + jsrc * 8,
                    (char*)Vts + c * 1024);
      }
    }
    __syncthreads();

    f32x4 S[4];
#pragma unroll
    for (int n = 0; n < 4; ++n) S[n] = f32x4{0.f, 0.f, 0.f, 0.f};
#pragma unroll
    for (int kk = 0; kk < 4; ++kk) {
#pragma unroll
      for (int n = 0; n < 4; ++n) {
        const int r = n * 16 + fr;
        const int p = (kk * 4 + fq) ^ (r & 7);
        short8 kf = *(const short8*)((const char*)Ks + r * 256 + p * 16);
        S[n] = __builtin_amdgcn_mfma_f32_16x16x32_bf16(qf[kk], kf, S[n], 0, 0, 0);
      }
    }

    float P[4][4];
    float tm[4] = {-1e30f, -1e30f, -1e30f, -1e30f};
#pragma unroll
    for (int n = 0; n < 4; ++n) {
      const int kv = kv0 + n * 16 + fr;
#pragma unroll
      for (int j = 0; j < 4; ++j) {
        const int qi = q0 + wid * 16 + fq * 4 + j;
        const float s = (kv <= qi) ? S[n][j] : -1e30f;
        P[n][j] = s;
        tm[j] = fmaxf(tm[j], s);
      }
    }
#pragma unroll
    for (int j = 0; j < 4; ++j)
#pragma unroll
      for (int msk = 1; msk < 16; msk <<= 1)
        tm[j] = fmaxf(tm[j], __shfl_xor(tm[j], msk));

    float al[4], rs[4];
#pragma unroll
    for (int j = 0; j < 4; ++j) {
      const float mn = fmaxf(mrun[j], tm[j]);
      al[j] = __expf(mrun[j] - mn);
      mrun[j] = mn;
      rs[j] = 0.f;
    }
#pragma unroll
    for (int n = 0; n < 4; ++n)
#pragma unroll
      for (int j = 0; j < 4; ++j) {
        const float p = __expf(P[n][j] - mrun[j]);
        P[n][j] = p;
        rs[j] += p;
      }
#pragma unroll
    for (int j = 0; j < 4; ++j) {
#pragma unroll
      for (int msk = 1; msk < 16; msk <<= 1) rs[j] += __shfl_xor(rs[j], msk);
      lrun[j] = lrun[j] * al[j] + rs[j];
    }
#pragma unroll
    for (int f = 0; f < 8; ++f) {
      f32x4 o = Oacc[f];
#pragma unroll
      for (int j = 0; j < 4; ++j) o[j] *= al[j];
      Oacc[f] = o;
    }

#pragma unroll
    for (int n = 0; n < 4; ++n)
#pragma unroll
      for (int j = 0; j < 4; ++j)
        Ps[wid][(fq * 4 + j) * 72 + n * 16 + fr] = f2b(P[n][j]);

#pragma unroll
    for (int kb = 0; kb < 2; ++kb) {
      short8 pa = *(const short8*)(Ps[wid] + fr * 72 + kb * 32 + fq * 8);
#pragma unroll
      for (int f = 0; f < 8; ++f) {
        const int d = f * 16 + fr;
        const int p = (kb * 4 + fq) ^ (d & 7);
        short8 vf = *(const short8*)((const char*)Vts + d * 128 + p * 16);
        Oacc[f] = __builtin_amdgcn_mfma_f32_16x16x32_bf16(pa, vf, Oacc[f], 0, 0, 0);
      }
    }
    __syncthreads();
  }

#pragma unroll
  for (int j = 0; j < 4; ++j) {
    const float inv = 1.f / lrun[j];
    const long r = q0 + wid * 16 + fq * 4 + j;
#pragma unroll
    for (int f = 0; f < 8; ++f)
      Ob[r * 4096 + h * 128 + f * 16 + fr] = f2b(Oacc[f][j] * inv);
  }
}

// ---------------- launch ----------------------------------------------------
extern "C" void kernel_launch(void* const* d_in, const int* in_sizes, int n_in,
                              void* d_out, int out_size, void* d_ws, size_t ws_size,
                              hipStream_t stream) {
  const float* hs   = (const float*)d_in[0];   // (2048, 4096)
  const float* cosb = (const float*)d_in[1];   // (2048, 128)
  const float* sinb = (const float*)d_in[2];   // (2048, 128)
  const float* wp   = (const float*)d_in[3];   // (12288, 4096)
  const float* wo   = (const float*)d_in[4];   // (4096, 4096)
  float* out = (float*)d_out;                  // (2048, 4096)
  char* ws = (char*)d_ws;

  // workspace (180 MB peak):
  //   [0,16M)    h_bf   -> reused by attn output after GEMM1
  //   [16M,116M) wp_bf  -> reused by wo_bf after GEMM1
  //   [116M,164M) qkv (q,k written; v region unused)
  //   [164M,180M) vt (4096 x 2048, written by GEMM1 epilogue)
  u16* h_bf  = (u16*)(ws);
  u16* attn  = (u16*)(ws);
  u16* wp_bf = (u16*)(ws + 16777216);
  u16* wo_bf = (u16*)(ws + 16777216);
  u16* qkv   = (u16*)(ws + 121634816);
  u16* vt    = (u16*)(ws + 171966464);

  cvt_hp<<<4096, 256, 0, stream>>>(hs, wp, h_bf, wp_bf);
  gemm256<0><<<768, 512, 0, stream>>>(h_bf, wp_bf, qkv, vt, 2048, 12288, 4096);
  cvt_bf16<<<2048, 256, 0, stream>>>(wo, wo_bf, 4194304);
  rope_qk<<<8192, 256, 0, stream>>>(qkv, cosb, sinb);
  attn_fwd<<<dim3(32, 32), 256, 0, stream>>>(qkv, qkv + 4096, vt, attn);
  gemm256<1><<<256, 512, 0, stream>>>(attn, wo_bf, out, nullptr, 2048, 4096, 4096);
}

// Round 6
// 537.015 us; speedup vs baseline: 1.4077x; 1.0279x over previous
//
#include <hip/hip_runtime.h>

typedef unsigned short u16;
typedef unsigned int   u32;
typedef __attribute__((ext_vector_type(8))) short short8;   // 8 x bf16
typedef __attribute__((ext_vector_type(4))) float f32x4;

__device__ __forceinline__ float b2f(u16 u) {
  union { float f; u32 i; } v; v.i = ((u32)u) << 16; return v.f;
}
__device__ __forceinline__ u16 f2b(float f) {
  union { float f; u32 i; } v; v.f = f;
  u32 r = v.i + 0x7fffu + ((v.i >> 16) & 1u);   // RNE
  return (u16)(r >> 16);
}

__device__ __forceinline__ void gload_lds16(const void* g, void* l) {
  __builtin_amdgcn_global_load_lds(
      (const __attribute__((address_space(1))) void*)g,
      (__attribute__((address_space(3))) void*)l, 16, 0, 0);
}

template <int N> __device__ __forceinline__ void wait_vmcnt() {
  if constexpr (N == 0)      asm volatile("s_waitcnt vmcnt(0)" ::: "memory");
  else if constexpr (N == 3) asm volatile("s_waitcnt vmcnt(3)" ::: "memory");
  else if constexpr (N == 4) asm volatile("s_waitcnt vmcnt(4)" ::: "memory");
  else if constexpr (N == 6) asm volatile("s_waitcnt vmcnt(6)" ::: "memory");
  else static_assert(N < 0, "unsupported vmcnt literal");
}

// ---------------- f32 -> bf16 converts ----------------
__device__ __forceinline__ ushort4 cvt4(float4 v) {
  ushort4 o;
  o.x = f2b(v.x); o.y = f2b(v.y); o.z = f2b(v.z); o.w = f2b(v.w);
  return o;
}

__global__ __launch_bounds__(256) void cvt_hp(const float* __restrict__ hs,
                                              const float* __restrict__ wp,
                                              u16* __restrict__ h_bf,
                                              u16* __restrict__ wp_bf) {
  const long H4 = 2097152, W4 = 12582912;   // float4 counts
  for (long i = (long)blockIdx.x * 256 + threadIdx.x; i < H4 + W4;
       i += (long)gridDim.x * 256) {
    if (i < H4)
      ((ushort4*)h_bf)[i] = cvt4(((const float4*)hs)[i]);
    else
      ((ushort4*)wp_bf)[i - H4] = cvt4(((const float4*)wp)[i - H4]);
  }
}

__global__ __launch_bounds__(256) void cvt_bf16(const float* __restrict__ in,
                                                u16* __restrict__ out, int n4) {
  for (long i = (long)blockIdx.x * 256 + threadIdx.x; i < n4; i += (long)gridDim.x * 256)
    ((ushort4*)out)[i] = cvt4(((const float4*)in)[i]);
}

// ============ GEMM1: 8-phase-class structure (m201 geometry) ================
// C(MxN) = A(MxK) * B(NxK)^T, bf16. Tile 256x256, BK=64, 8 waves (2M x 4N),
// per-wave 128x64. LDS 2 x 64KB double buffer. 4 phases/K-tile, 16 MFMA each.
// Stage 1 half-tile (2 gload_lds) per phase; counted vmcnt(4) once per K-tile.
// Swizzle: row = 8 x 16B chunks, phys = logical ^ (row&7); linear LDS dest +
// pre-swizzled global source. Proven slot lifetimes:
//   A-halves of buf(t) free after ph3(t); B-halves after ph2(t).
//   ph1(t): stage A-lo(t+1) | ph2: A-hi(t+1) | ph3: B-lo(t+2) | ph4: B-hi(t+2)
// Every tile fully landed >=4 phases before first read (vmcnt(4) at ph4).
// EPI 0: u16 C into qkv; blocks with col0>=8192 write transposed into VT.
__device__ __forceinline__ short8 frag_ld64(const u16* base, int rbase, int kk,
                                            int fr, int fq) {
  const int r = rbase + fr;
  return *(const short8*)(base + r * 64 + ((((kk << 2) + fq) ^ (r & 7)) << 3));
}

template <int EPI>
__global__ __launch_bounds__(512, 2) void gemm8p(const u16* __restrict__ A,
                                                 const u16* __restrict__ B,
                                                 void* __restrict__ Cv,
                                                 u16* __restrict__ VT,
                                                 int M, int N, int K) {
  constexpr int BUFSZ = 32768;              // u16 per buffer (A 16384 | B 16384)
  __shared__ u16 lds[2 * BUFSZ];            // 128 KiB
  const int tid = threadIdx.x;
  const int wid = tid >> 6, lane = tid & 63;
  const int fr = lane & 15, fq = lane >> 4;
  const int mA = (wid >> 2) * 128;          // wm in {0,1}
  const int nB = (wid & 3) * 64;            // wn in {0..3}

  // XCD-chunked column-major tile mapping (grid % 8 == 0)
  const int nty = M >> 8;
  const int qx = gridDim.x >> 3;
  const int wg = (blockIdx.x & 7) * qx + (blockIdx.x >> 3);
  const int by = wg % nty, bx = wg / nty;
  const long row0 = (long)by * 256, col0 = (long)bx * 256;

  // staging geometry: chunk c = h*1024 + i*512 + tid  (h=half, i=0/1)
  //   r = h*128 + i*64 + (tid>>3), phys = tid&7, logical = phys ^ (r&7)
  //   (r&7) == ((tid>>3)&7) since h*128, i*64 are multiples of 8.
  const int rr = tid >> 3;
  const int jl = (tid & 7) ^ (rr & 7);
  const u16* gAb = A + (row0 + rr) * (long)K + jl * 8;
  const u16* gBb = B + (col0 + rr) * (long)K + jl * 8;
  const int dAb = tid * 8;

  f32x4 acc[8][4];
#pragma unroll
  for (int m = 0; m < 8; ++m)
#pragma unroll
    for (int n = 0; n < 4; ++n) acc[m][n] = f32x4{0.f, 0.f, 0.f, 0.f};

  const int NT = K >> 6;                    // BK = 64

  auto stageA = [&](int h, int t) {
    u16* d = lds + (t & 1) * BUFSZ + h * 8192 + dAb;
    const u16* s = gAb + (long)(h * 128) * K + (long)t * 64;
    gload_lds16(s, d);
    gload_lds16(s + (long)64 * K, d + 4096);
  };
  auto stageB = [&](int h, int t) {
    u16* d = lds + (t & 1) * BUFSZ + 16384 + h * 8192 + dAb;
    const u16* s = gBb + (long)(h * 128) * K + (long)t * 64;
    gload_lds16(s, d);
    gload_lds16(s + (long)64 * K, d + 4096);
  };

  // prologue: tile0 full + B(1); vmcnt(4) retires tile0, keeps B(1) in flight
  stageA(0, 0); stageA(1, 0); stageB(0, 0); stageB(1, 0);
  stageB(0, 1); stageB(1, 1);
  wait_vmcnt<4>();
  __builtin_amdgcn_s_barrier();

  for (int t = 0; t < NT; ++t) {
    const u16* SA = lds + (t & 1) * BUFSZ;
    const u16* SB = SA + 16384;
    short8 af[4][2], b0f[2][2], b1f[2][2];

    // ---- phase 1: quadrant (qm0, qn0); stage A-lo(t+1) ----
#pragma unroll
    for (int m = 0; m < 4; ++m)
#pragma unroll
      for (int kk = 0; kk < 2; ++kk)
        af[m][kk] = frag_ld64(SA, mA + m * 16, kk, fr, fq);
#pragma unroll
    for (int n = 0; n < 2; ++n)
#pragma unroll
      for (int kk = 0; kk < 2; ++kk)
        b0f[n][kk] = frag_ld64(SB, nB + n * 16, kk, fr, fq);
    if (t + 1 < NT) stageA(0, t + 1);
    __builtin_amdgcn_s_setprio(1);
#pragma unroll
    for (int m = 0; m < 4; ++m)
#pragma unroll
      for (int n = 0; n < 2; ++n)
#pragma unroll
        for (int kk = 0; kk < 2; ++kk)
          acc[m][n] = __builtin_amdgcn_mfma_f32_16x16x32_bf16(af[m][kk], b0f[n][kk], acc[m][n], 0, 0, 0);
    __builtin_amdgcn_s_setprio(0);
    __builtin_amdgcn_s_barrier();

    // ---- phase 2: (qm0, qn1); stage A-hi(t+1) ----
#pragma unroll
    for (int n = 0; n < 2; ++n)
#pragma unroll
      for (int kk = 0; kk < 2; ++kk)
        b1f[n][kk] = frag_ld64(SB, nB + 32 + n * 16, kk, fr, fq);
    if (t + 1 < NT) stageA(1, t + 1);
    __builtin_amdgcn_s_setprio(1);
#pragma unroll
    for (int m = 0; m < 4; ++m)
#pragma unroll
      for (int n = 0; n < 2; ++n)
#pragma unroll
        for (int kk = 0; kk < 2; ++kk)
          acc[m][2 + n] = __builtin_amdgcn_mfma_f32_16x16x32_bf16(af[m][kk], b1f[n][kk], acc[m][2 + n], 0, 0, 0);
    __builtin_amdgcn_s_setprio(0);
    __builtin_amdgcn_s_barrier();

    // ---- phase 3: (qm1, qn0); stage B-lo(t+2) ----
#pragma unroll
    for (int m = 0; m < 4; ++m)
#pragma unroll
      for (int kk = 0; kk < 2; ++kk)
        af[m][kk] = frag_ld64(SA, mA + 64 + m * 16, kk, fr, fq);
    if (t + 2 < NT) stageB(0, t + 2);
    __builtin_amdgcn_s_setprio(1);
#pragma unroll
    for (int m = 0; m < 4; ++m)
#pragma unroll
      for (int n = 0; n < 2; ++n)
#pragma unroll
        for (int kk = 0; kk < 2; ++kk)
          acc[4 + m][n] = __builtin_amdgcn_mfma_f32_16x16x32_bf16(af[m][kk], b0f[n][kk], acc[4 + m][n], 0, 0, 0);
    __builtin_amdgcn_s_setprio(0);
    __builtin_amdgcn_s_barrier();

    // ---- phase 4: (qm1, qn1); stage B-hi(t+2); counted vmcnt ----
    if (t + 2 < NT) stageB(1, t + 2);
    __builtin_amdgcn_s_setprio(1);
#pragma unroll
    for (int m = 0; m < 4; ++m)
#pragma unroll
      for (int n = 0; n < 2; ++n)
#pragma unroll
        for (int kk = 0; kk < 2; ++kk)
          acc[4 + m][2 + n] = __builtin_amdgcn_mfma_f32_16x16x32_bf16(af[m][kk], b1f[n][kk], acc[4 + m][2 + n], 0, 0, 0);
    __builtin_amdgcn_s_setprio(0);
    if (t + 2 < NT) wait_vmcnt<4>();
    else            wait_vmcnt<0>();
    __builtin_amdgcn_s_barrier();
  }

  if constexpr (EPI == 0) {
    if (col0 >= 8192) {
      // V block: write transposed into VT (4096 x 2048)
#pragma unroll
      for (int m = 0; m < 8; ++m)
#pragma unroll
        for (int n = 0; n < 4; ++n) {
          const long vcol = col0 - 8192 + nB + n * 16 + fr;
          const long rbase = row0 + mA + m * 16 + fq * 4;
          ushort4 o;
          o.x = f2b(acc[m][n][0]); o.y = f2b(acc[m][n][1]);
          o.z = f2b(acc[m][n][2]); o.w = f2b(acc[m][n][3]);
          *(ushort4*)(VT + vcol * 2048 + rbase) = o;
        }
    } else {
      u16* C = (u16*)Cv;
#pragma unroll
      for (int m = 0; m < 8; ++m)
#pragma unroll
        for (int n = 0; n < 4; ++n)
#pragma unroll
          for (int j = 0; j < 4; ++j) {
            const long r = row0 + mA + m * 16 + fq * 4 + j;
            const long c = col0 + nB + n * 16 + fr;
            C[r * N + c] = f2b(acc[m][n][j]);
          }
    }
  } else {
    float* C = (float*)Cv;
#pragma unroll
    for (int m = 0; m < 8; ++m)
#pragma unroll
      for (int n = 0; n < 4; ++n)
#pragma unroll
        for (int j = 0; j < 4; ++j) {
          const long r = row0 + mA + m * 16 + fq * 4 + j;
          const long c = col0 + nB + n * 16 + fr;
          C[r * N + c] = acc[m][n][j];
        }
  }
}

// ============ GEMM2: proven R2 structure (float out) ========================
__device__ __forceinline__ short8 frag_ld(const u16* base, int rbase, int fr, int fq) {
  const int r = rbase + fr;
  return *(const short8*)(base + r * 32 + ((fq ^ ((r >> 1) & 3)) << 3));
}

__global__ __launch_bounds__(512, 2) void gemm256(const u16* __restrict__ A,
                                                  const u16* __restrict__ B,
                                                  float* __restrict__ C,
                                                  int M, int N, int K) {
  __shared__ u16 lds[4 * 12288];          // 4 slots x (A 8192 + B 4096) u16
  const int tid = threadIdx.x;
  const int wid = tid >> 6, lane = tid & 63;
  const int fr = lane & 15, fq = lane >> 4;
  const int mA = (wid >> 1) * 64;
  const int nB = (wid & 1) * 64;

  const int nty = M >> 8;
  const int q = gridDim.x >> 3;
  const int wg = (blockIdx.x & 7) * q + (blockIdx.x >> 3);
  const int by = wg % nty;
  const int bx = wg / nty;
  const long row0 = (long)by * 256;
  const long col0 = (long)bx * 128;

  const int c0 = tid, c1 = 512 + tid, cB = tid;
  const int rA0 = c0 >> 2, j0 = (c0 & 3) ^ ((rA0 >> 1) & 3);
  const int rA1 = c1 >> 2, j1 = (c1 & 3) ^ ((rA1 >> 1) & 3);
  const int rB  = cB >> 2, j2 = (cB & 3) ^ ((rB >> 1) & 3);
  const u16* gA0 = A + (row0 + rA0) * (long)K + j0 * 8;
  const u16* gA1 = A + (row0 + rA1) * (long)K + j1 * 8;
  const u16* gB  = B + (col0 + rB) * (long)K + j2 * 8;
  const int dA0 = c0 * 8, dA1 = c1 * 8, dB = 8192 + cB * 8;

  f32x4 acc[4][4];
#pragma unroll
  for (int m = 0; m < 4; ++m)
#pragma unroll
    for (int n = 0; n < 4; ++n) acc[m][n] = f32x4{0.f, 0.f, 0.f, 0.f};

  const int NT = K >> 5;

#pragma unroll
  for (int pt = 0; pt < 3; ++pt) {
    u16* s = lds + pt * 12288;
    gload_lds16(gA0 + pt * 32, s + dA0);
    gload_lds16(gA1 + pt * 32, s + dA1);
    gload_lds16(gB  + pt * 32, s + dB);
  }
  wait_vmcnt<6>();
  __builtin_amdgcn_s_barrier();

  for (int t = 0; t < NT; ++t) {
    const u16* SA = lds + (t & 3) * 12288;
    const u16* SB = SA + 8192;
    u16* ST = lds + ((t + 3) & 3) * 12288;
    const bool st = (t + 3) < NT;
    const int sk = (t + 3) * 32;

    short8 a0 = frag_ld(SA, mA +  0, fr, fq);
    short8 a1 = frag_ld(SA, mA + 16, fr, fq);
    short8 b0 = frag_ld(SB, nB +  0, fr, fq);
    short8 b1 = frag_ld(SB, nB + 16, fr, fq);
    short8 b2 = frag_ld(SB, nB + 32, fr, fq);
    short8 b3 = frag_ld(SB, nB + 48, fr, fq);
    if (st) {
      gload_lds16(gA0 + sk, ST + dA0);
      gload_lds16(gA1 + sk, ST + dA1);
    }
    __builtin_amdgcn_s_barrier();
    __builtin_amdgcn_s_setprio(1);
    acc[0][0] = __builtin_amdgcn_mfma_f32_16x16x32_bf16(a0, b0, acc[0][0], 0, 0, 0);
    acc[0][1] = __builtin_amdgcn_mfma_f32_16x16x32_bf16(a0, b1, acc[0][1], 0, 0, 0);
    acc[0][2] = __builtin_amdgcn_mfma_f32_16x16x32_bf16(a0, b2, acc[0][2], 0, 0, 0);
    acc[0][3] = __builtin_amdgcn_mfma_f32_16x16x32_bf16(a0, b3, acc[0][3], 0, 0, 0);
    acc[1][0] = __builtin_amdgcn_mfma_f32_16x16x32_bf16(a1, b0, acc[1][0], 0, 0, 0);
    acc[1][1] = __builtin_amdgcn_mfma_f32_16x16x32_bf16(a1, b1, acc[1][1], 0, 0, 0);
    acc[1][2] = __builtin_amdgcn_mfma_f32_16x16x32_bf16(a1, b2, acc[1][2], 0, 0, 0);
    acc[1][3] = __builtin_amdgcn_mfma_f32_16x16x32_bf16(a1, b3, acc[1][3], 0, 0, 0);
    __builtin_amdgcn_s_setprio(0);
    __builtin_amdgcn_s_barrier();

    short8 a2 = frag_ld(SA, mA + 32, fr, fq);
    short8 a3 = frag_ld(SA, mA + 48, fr, fq);
    if (st) gload_lds16(gB + sk, ST + dB);
    __builtin_amdgcn_s_barrier();
    __builtin_amdgcn_s_setprio(1);
    acc[2][0] = __builtin_amdgcn_mfma_f32_16x16x32_bf16(a2, b0, acc[2][0], 0, 0, 0);
    acc[2][1] = __builtin_amdgcn_mfma_f32_16x16x32_bf16(a2, b1, acc[2][1], 0, 0, 0);
    acc[2][2] = __builtin_amdgcn_mfma_f32_16x16x32_bf16(a2, b2, acc[2][2], 0, 0, 0);
    acc[2][3] = __builtin_amdgcn_mfma_f32_16x16x32_bf16(a2, b3, acc[2][3], 0, 0, 0);
    acc[3][0] = __builtin_amdgcn_mfma_f32_16x16x32_bf16(a3, b0, acc[3][0], 0, 0, 0);
    acc[3][1] = __builtin_amdgcn_mfma_f32_16x16x32_bf16(a3, b1, acc[3][1], 0, 0, 0);
    acc[3][2] = __builtin_amdgcn_mfma_f32_16x16x32_bf16(a3, b2, acc[3][2], 0, 0, 0);
    acc[3][3] = __builtin_amdgcn_mfma_f32_16x16x32_bf16(a3, b3, acc[3][3], 0, 0, 0);
    __builtin_amdgcn_s_setprio(0);
    if (t + 3 < NT)      wait_vmcnt<6>();
    else if (t + 2 < NT) wait_vmcnt<3>();
    else                 wait_vmcnt<0>();
    __builtin_amdgcn_s_barrier();
  }

#pragma unroll
  for (int m = 0; m < 4; ++m)
#pragma unroll
    for (int n = 0; n < 4; ++n)
#pragma unroll
      for (int j = 0; j < 4; ++j) {
        const long r = row0 + mA + m * 16 + fq * 4 + j;
        const long c = col0 + nB + n * 16 + fr;
        C[r * N + c] = acc[m][n][j];
      }
}

// ---------------- RoPE on q,k (vectorized) ---------------------------------
__global__ __launch_bounds__(256) void rope_qk(u16* __restrict__ qkv,
                                               const float* __restrict__ cosb,
                                               const float* __restrict__ sinb) {
  const int idx = blockIdx.x * 256 + threadIdx.x;   // grid exact: 2,097,152
  const int dq  = idx & 15;
  const int h   = (idx >> 4) & 31;
  const int seg = (idx >> 9) & 1;                   // 0 = q, 1 = k
  const int s   = idx >> 10;
  const int d0  = dq * 4;
  u16* base = qkv + (long)s * 12288 + seg * 4096 + h * 128;
  const ushort4 x1 = *(const ushort4*)(base + d0);
  const ushort4 x2 = *(const ushort4*)(base + d0 + 64);
  const float4 c1 = *(const float4*)(cosb + s * 128 + d0);
  const float4 s1 = *(const float4*)(sinb + s * 128 + d0);
  const float4 c2 = *(const float4*)(cosb + s * 128 + d0 + 64);
  const float4 s2 = *(const float4*)(sinb + s * 128 + d0 + 64);
  const float scale = seg ? 1.0f : 0.08838834764831845f;   // 1/sqrt(128) on q
  float x1f[4] = {b2f(x1.x), b2f(x1.y), b2f(x1.z), b2f(x1.w)};
  float x2f[4] = {b2f(x2.x), b2f(x2.y), b2f(x2.z), b2f(x2.w)};
  const float c1a[4] = {c1.x, c1.y, c1.z, c1.w}, s1a[4] = {s1.x, s1.y, s1.z, s1.w};
  const float c2a[4] = {c2.x, c2.y, c2.z, c2.w}, s2a[4] = {s2.x, s2.y, s2.z, s2.w};
  ushort4 o1, o2;
  u16* o1p = (u16*)&o1; u16* o2p = (u16*)&o2;
#pragma unroll
  for (int j = 0; j < 4; ++j) {
    o1p[j] = f2b((x1f[j] * c1a[j] - x2f[j] * s1a[j]) * scale);
    o2p[j] = f2b((x2f[j] * c2a[j] + x1f[j] * s2a[j]) * scale);
  }
  *(ushort4*)(base + d0) = o1;
  *(ushort4*)(base + d0 + 64) = o2;
}

// ---------------- causal flash attention ------------------------------------
__global__ __launch_bounds__(256) void attn_fwd(const u16* __restrict__ Qb,
                                                const u16* __restrict__ Kb,
                                                const u16* __restrict__ Vt,
                                                u16* __restrict__ Ob) {
  const int h  = blockIdx.y;
  const int q0 = blockIdx.x * 64;
  const int tid = threadIdx.x;
  const int wid = tid >> 6, lane = tid & 63;
  const int fr = lane & 15, fq = lane >> 4;

  __shared__ u16 Ks[64 * 128];
  __shared__ u16 Vts[128 * 64];
  __shared__ u16 Ps[4][16 * 72];

  short8 qf[4];
  {
    const long qrow = q0 + wid * 16 + fr;
#pragma unroll
    for (int kk = 0; kk < 4; ++kk)
      qf[kk] = *(const short8*)(Qb + qrow * 12288 + h * 128 + kk * 32 + fq * 8);
  }

  f32x4 Oacc[8];
#pragma unroll
  for (int f = 0; f < 8; ++f) Oacc[f] = f32x4{0.f, 0.f, 0.f, 0.f};
  float mrun[4], lrun[4];
#pragma unroll
  for (int j = 0; j < 4; ++j) { mrun[j] = -1e30f; lrun[j] = 0.f; }

  const int nt = blockIdx.x + 1;
  for (int t = 0; t < nt; ++t) {
    const int kv0 = t * 64;
#pragma unroll
    for (int i = 0; i < 4; ++i) {
      const int c = wid * 4 + i;
      {
        const int r = c * 4 + (lane >> 4);
        const int p = lane & 15;
        const int jsrc = p ^ (r & 7);
        gload_lds16(Kb + (long)(kv0 + r) * 12288 + h * 128 + jsrc * 8,
                    (char*)Ks + c * 1024);
      }
      {
        const int d = c * 8 + (lane >> 3);
        const int p = lane & 7;
        const int jsrc = p ^ (d & 7);
        gload_lds16(Vt + (long)(h * 128 + d) * 2048 + kv0 + jsrc * 8,
                    (char*)Vts + c * 1024);
      }
    }
    __syncthreads();

    f32x4 S[4];
#pragma unroll
    for (int n = 0; n < 4; ++n) S[n] = f32x4{0.f, 0.f, 0.f, 0.f};
#pragma unroll
    for (int kk = 0; kk < 4; ++kk) {
#pragma unroll
      for (int n = 0; n < 4; ++n) {
        const int r = n * 16 + fr;
        const int p = (kk * 4 + fq) ^ (r & 7);
        short8 kf = *(const short8*)((const char*)Ks + r * 256 + p * 16);
        S[n] = __builtin_amdgcn_mfma_f32_16x16x32_bf16(qf[kk], kf, S[n], 0, 0, 0);
      }
    }

    float P[4][4];
    float tm[4] = {-1e30f, -1e30f, -1e30f, -1e30f};
#pragma unroll
    for (int n = 0; n < 4; ++n) {
      const int kv = kv0 + n * 16 + fr;
#pragma unroll
      for (int j = 0; j < 4; ++j) {
        const int qi = q0 + wid * 16 + fq * 4 + j;
        const float s = (kv <= qi) ? S[n][j] : -1e30f;
        P[n][j] = s;
        tm[j] = fmaxf(tm[j], s);
      }
    }
#pragma unroll
    for (int j = 0; j < 4; ++j)
#pragma unroll
      for (int msk = 1; msk < 16; msk <<= 1)
        tm[j] = fmaxf(tm[j], __shfl_xor(tm[j], msk));

    float al[4], rs[4];
#pragma unroll
    for (int j = 0; j < 4; ++j) {
      const float mn = fmaxf(mrun[j], tm[j]);
      al[j] = __expf(mrun[j] - mn);
      mrun[j] = mn;
      rs[j] = 0.f;
    }
#pragma unroll
    for (int n = 0; n < 4; ++n)
#pragma unroll
      for (int j = 0; j < 4; ++j) {
        const float p = __expf(P[n][j] - mrun[j]);
        P[n][j] = p;
        rs[j] += p;
      }
#pragma unroll
    for (int j = 0; j < 4; ++j) {
#pragma unroll
      for (int msk = 1; msk < 16; msk <<= 1) rs[j] += __shfl_xor(rs[j], msk);
      lrun[j] = lrun[j] * al[j] + rs[j];
    }
#pragma unroll
    for (int f = 0; f < 8; ++f) {
      f32x4 o = Oacc[f];
#pragma unroll
      for (int j = 0; j < 4; ++j) o[j] *= al[j];
      Oacc[f] = o;
    }

#pragma unroll
    for (int n = 0; n < 4; ++n)
#pragma unroll
      for (int j = 0; j < 4; ++j)
        Ps[wid][(fq * 4 + j) * 72 + n * 16 + fr] = f2b(P[n][j]);

#pragma unroll
    for (int kb = 0; kb < 2; ++kb) {
      short8 pa = *(const short8*)(Ps[wid] + fr * 72 + kb * 32 + fq * 8);
#pragma unroll
      for (int f = 0; f < 8; ++f) {
        const int d = f * 16 + fr;
        const int p = (kb * 4 + fq) ^ (d & 7);
        short8 vf = *(const short8*)((const char*)Vts + d * 128 + p * 16);
        Oacc[f] = __builtin_amdgcn_mfma_f32_16x16x32_bf16(pa, vf, Oacc[f], 0, 0, 0);
      }
    }
    __syncthreads();
  }

#pragma unroll
  for (int j = 0; j < 4; ++j) {
    const float inv = 1.f / lrun[j];
    const long r = q0 + wid * 16 + fq * 4 + j;
#pragma unroll
    for (int f = 0; f < 8; ++f)
      Ob[r * 4096 + h * 128 + f * 16 + fr] = f2b(Oacc[f][j] * inv);
  }
}

// ---------------- launch ----------------------------------------------------
extern "C" void kernel_launch(void* const* d_in, const int* in_sizes, int n_in,
                              void* d_out, int out_size, void* d_ws, size_t ws_size,
                              hipStream_t stream) {
  const float* hs   = (const float*)d_in[0];   // (2048, 4096)
  const float* cosb = (const float*)d_in[1];   // (2048, 128)
  const float* sinb = (const float*)d_in[2];   // (2048, 128)
  const float* wp   = (const float*)d_in[3];   // (12288, 4096)
  const float* wo   = (const float*)d_in[4];   // (4096, 4096)
  float* out = (float*)d_out;                  // (2048, 4096)
  char* ws = (char*)d_ws;

  // workspace (180 MB peak):
  //   [0,16M)    h_bf   -> reused by attn output after GEMM1
  //   [16M,116M) wp_bf  -> reused by wo_bf after GEMM1
  //   [116M,164M) qkv (q,k written; v region unused)
  //   [164M,180M) vt (4096 x 2048, written by GEMM1 epilogue)
  u16* h_bf  = (u16*)(ws);
  u16* attn  = (u16*)(ws);
  u16* wp_bf = (u16*)(ws + 16777216);
  u16* wo_bf = (u16*)(ws + 16777216);
  u16* qkv   = (u16*)(ws + 121634816);
  u16* vt    = (u16*)(ws + 171966464);

  cvt_hp<<<4096, 256, 0, stream>>>(hs, wp, h_bf, wp_bf);
  gemm8p<0><<<384, 512, 0, stream>>>(h_bf, wp_bf, qkv, vt, 2048, 12288, 4096);
  cvt_bf16<<<2048, 256, 0, stream>>>(wo, wo_bf, 4194304);
  rope_qk<<<8192, 256, 0, stream>>>(qkv, cosb, sinb);
  attn_fwd<<<dim3(32, 32), 256, 0, stream>>>(qkv, qkv + 4096, vt, attn);
  gemm256<<<256, 512, 0, stream>>>(attn, wo_bf, out, 2048, 4096, 4096);
}

// Round 7
// 508.759 us; speedup vs baseline: 1.4859x; 1.0555x over previous
//
#include <hip/hip_runtime.h>

typedef unsigned short u16;
typedef unsigned int   u32;
typedef __attribute__((ext_vector_type(8))) short short8;   // 8 x bf16
typedef __attribute__((ext_vector_type(4))) float f32x4;

__device__ __forceinline__ float b2f(u16 u) {
  union { float f; u32 i; } v; v.i = ((u32)u) << 16; return v.f;
}
__device__ __forceinline__ u16 f2b(float f) {
  union { float f; u32 i; } v; v.f = f;
  u32 r = v.i + 0x7fffu + ((v.i >> 16) & 1u);   // RNE
  return (u16)(r >> 16);
}

__device__ __forceinline__ void gload_lds16(const void* g, void* l) {
  __builtin_amdgcn_global_load_lds(
      (const __attribute__((address_space(1))) void*)g,
      (__attribute__((address_space(3))) void*)l, 16, 0, 0);
}

template <int N> __device__ __forceinline__ void wait_vmcnt() {
  if constexpr (N == 0)      asm volatile("s_waitcnt vmcnt(0)" ::: "memory");
  else if constexpr (N == 3) asm volatile("s_waitcnt vmcnt(3)" ::: "memory");
  else if constexpr (N == 6) asm volatile("s_waitcnt vmcnt(6)" ::: "memory");
  else static_assert(N < 0, "unsupported vmcnt literal");
}

// ---------------- f32 -> bf16 converts ----------------
__device__ __forceinline__ ushort4 cvt4(float4 v) {
  ushort4 o;
  o.x = f2b(v.x); o.y = f2b(v.y); o.z = f2b(v.z); o.w = f2b(v.w);
  return o;
}

__global__ __launch_bounds__(256) void cvt_hp(const float* __restrict__ hs,
                                              const float* __restrict__ wp,
                                              u16* __restrict__ h_bf,
                                              u16* __restrict__ wp_bf) {
  const long H4 = 2097152, W4 = 12582912;   // float4 counts
  for (long i = (long)blockIdx.x * 256 + threadIdx.x; i < H4 + W4;
       i += (long)gridDim.x * 256) {
    if (i < H4)
      ((ushort4*)h_bf)[i] = cvt4(((const float4*)hs)[i]);
    else
      ((ushort4*)wp_bf)[i - H4] = cvt4(((const float4*)wp)[i - H4]);
  }
}

__global__ __launch_bounds__(256) void cvt_bf16(const float* __restrict__ in,
                                                u16* __restrict__ out, int n4) {
  for (long i = (long)blockIdx.x * 256 + threadIdx.x; i < n4; i += (long)gridDim.x * 256)
    ((ushort4*)out)[i] = cvt4(((const float4*)in)[i]);
}

// ============ GEMM1: 4-phase, tile 256x192 (balanced 512-block grid) ========
// C(MxN) = A(MxK) * B(NxK)^T, bf16. BK=64, 8 waves (2M x 4N), per-wave 128x48.
// LDS 2 x 57344B double buffer (114.7 KiB). 4 phases x 12 MFMA per K-tile.
// ph1: read aA(kk0)+ALL 6 B frags, stage A-half0(t+1), MFMA, lgkm(0), barrier
// ph2: read aB(kk0),               stage A-half1(t+1), MFMA, barrier
// ph3: read aA(kk1),               stage B-2/3(t+2),   MFMA, barrier
// ph4: read aB(kk1),               stage B-1/3(t+2),   MFMA, vmcnt(3), barrier
// B(t+2) -> buf(t) B-region is safe: all B(t) reads retired at ph1's lgkm(0).
// Counted vmcnt never drains mid-loop (T4). Swizzle: phys16B = logical^(row&7),
// linear LDS dest + pre-swizzled global source (rule 21).
// Epilogue: per-fragment (16-col aligned) split: cols>=8192 -> VT transposed.
__device__ __forceinline__ short8 frag_ld64(const u16* base, int rbase, int kk,
                                            int fr, int fq) {
  const int r = rbase + fr;
  return *(const short8*)(base + r * 64 + ((((kk << 2) + fq) ^ (r & 7)) << 3));
}

__global__ __launch_bounds__(512, 2) void gemm8p(const u16* __restrict__ A,
                                                 const u16* __restrict__ B,
                                                 u16* __restrict__ Cq,
                                                 u16* __restrict__ VT,
                                                 int M, int N, int K) {
  constexpr int AE = 16384;                 // A region u16 (256x64)
  constexpr int BUFSZ = AE + 12288;         // + B region (192x64) = 28672 u16
  __shared__ u16 lds[2 * BUFSZ];            // 114,688 B
  const int tid = threadIdx.x;
  const int wid = tid >> 6, lane = tid & 63;
  const int fr = lane & 15, fq = lane >> 4;
  const int mA = (wid >> 2) * 128;          // wm in {0,1}
  const int nB = (wid & 3) * 48;            // wn in {0..3}

  // XCD-chunked column-major tile mapping (grid % 8 == 0)
  const int nty = M >> 8;                   // 8
  const int qx = gridDim.x >> 3;
  const int wg = (blockIdx.x & 7) * qx + (blockIdx.x >> 3);
  const int by = wg % nty, bx = wg / nty;
  const long row0 = (long)by * 256, col0 = (long)bx * 192;

  // staging: chunk c = i*512 + tid; row r = c>>3, phys slot = c&7,
  // logical slot = phys ^ (r&7); r = i*64 + (tid>>3) (i*64 % 8 == 0).
  const int rr8 = tid >> 3;
  const int jl = (tid & 7) ^ (rr8 & 7);
  const u16* gA = A + (row0 + rr8) * (long)K + jl * 8;
  const u16* gB = B + (col0 + rr8) * (long)K + jl * 8;

  f32x4 acc[8][3];
#pragma unroll
  for (int m = 0; m < 8; ++m)
#pragma unroll
    for (int n = 0; n < 3; ++n) acc[m][n] = f32x4{0.f, 0.f, 0.f, 0.f};

  const int NT = K >> 6;                    // BK = 64

  auto stageA = [&](int i, int t) {
    gload_lds16(gA + (long)(i * 64) * K + (long)t * 64,
                lds + (t & 1) * BUFSZ + (i * 512 + tid) * 8);
  };
  auto stageB = [&](int i, int t) {
    gload_lds16(gB + (long)(i * 64) * K + (long)t * 64,
                lds + (t & 1) * BUFSZ + AE + (i * 512 + tid) * 8);
  };

  // prologue: A(0) x4, B(0) x3, B(1) x3; vmcnt(3) retires A(0),B(0)
#pragma unroll
  for (int i = 0; i < 4; ++i) stageA(i, 0);
#pragma unroll
  for (int i = 0; i < 3; ++i) stageB(i, 0);
#pragma unroll
  for (int i = 0; i < 3; ++i) stageB(i, 1);
  wait_vmcnt<3>();
  __builtin_amdgcn_s_barrier();

  for (int t = 0; t < NT; ++t) {
    const u16* SA = lds + (t & 1) * BUFSZ;
    const u16* SB = SA + AE;
    short8 a0[4], a1[4], b0[3], b1[3];

    // ---- phase 1: (qm0,kk0); all B frags; stage A i=0,1 ----
#pragma unroll
    for (int m = 0; m < 4; ++m) a0[m] = frag_ld64(SA, mA + m * 16, 0, fr, fq);
#pragma unroll
    for (int n = 0; n < 3; ++n) b0[n] = frag_ld64(SB, nB + n * 16, 0, fr, fq);
#pragma unroll
    for (int n = 0; n < 3; ++n) b1[n] = frag_ld64(SB, nB + n * 16, 1, fr, fq);
    if (t + 1 < NT) { stageA(0, t + 1); stageA(1, t + 1); }
    __builtin_amdgcn_s_setprio(1);
#pragma unroll
    for (int m = 0; m < 4; ++m)
#pragma unroll
      for (int n = 0; n < 3; ++n)
        acc[m][n] = __builtin_amdgcn_mfma_f32_16x16x32_bf16(a0[m], b0[n], acc[m][n], 0, 0, 0);
    __builtin_amdgcn_s_setprio(0);
    asm volatile("s_waitcnt lgkmcnt(0)" ::: "memory");   // all B(t) reads retired
    __builtin_amdgcn_s_barrier();

    // ---- phase 2: (qm1,kk0); stage A i=2,3 ----
#pragma unroll
    for (int m = 0; m < 4; ++m) a1[m] = frag_ld64(SA, mA + 64 + m * 16, 0, fr, fq);
    if (t + 1 < NT) { stageA(2, t + 1); stageA(3, t + 1); }
    __builtin_amdgcn_s_setprio(1);
#pragma unroll
    for (int m = 0; m < 4; ++m)
#pragma unroll
      for (int n = 0; n < 3; ++n)
        acc[4 + m][n] = __builtin_amdgcn_mfma_f32_16x16x32_bf16(a1[m], b0[n], acc[4 + m][n], 0, 0, 0);
    __builtin_amdgcn_s_setprio(0);
    __builtin_amdgcn_s_barrier();

    // ---- phase 3: (qm0,kk1); stage B i=0,1 into buf(t) B-region ----
#pragma unroll
    for (int m = 0; m < 4; ++m) a0[m] = frag_ld64(SA, mA + m * 16, 1, fr, fq);
    if (t + 2 < NT) { stageB(0, t + 2); stageB(1, t + 2); }
    __builtin_amdgcn_s_setprio(1);
#pragma unroll
    for (int m = 0; m < 4; ++m)
#pragma unroll
      for (int n = 0; n < 3; ++n)
        acc[m][n] = __builtin_amdgcn_mfma_f32_16x16x32_bf16(a0[m], b1[n], acc[m][n], 0, 0, 0);
    __builtin_amdgcn_s_setprio(0);
    __builtin_amdgcn_s_barrier();

    // ---- phase 4: (qm1,kk1); stage B i=2; counted vmcnt ----
#pragma unroll
    for (int m = 0; m < 4; ++m) a1[m] = frag_ld64(SA, mA + 64 + m * 16, 1, fr, fq);
    if (t + 2 < NT) stageB(2, t + 2);
    __builtin_amdgcn_s_setprio(1);
#pragma unroll
    for (int m = 0; m < 4; ++m)
#pragma unroll
      for (int n = 0; n < 3; ++n)
        acc[4 + m][n] = __builtin_amdgcn_mfma_f32_16x16x32_bf16(a1[m], b1[n], acc[4 + m][n], 0, 0, 0);
    __builtin_amdgcn_s_setprio(0);
    if (t + 2 < NT) wait_vmcnt<3>();
    else            wait_vmcnt<0>();
    __builtin_amdgcn_s_barrier();
  }

  // epilogue: per-fragment split (fragments are 16-col aligned; 8192%16==0)
#pragma unroll
  for (int m = 0; m < 8; ++m)
#pragma unroll
    for (int n = 0; n < 3; ++n) {
      const long c = col0 + nB + n * 16 + fr;
      const long rb = row0 + mA + m * 16 + fq * 4;
      if (c >= 8192) {
        ushort4 o;
        o.x = f2b(acc[m][n][0]); o.y = f2b(acc[m][n][1]);
        o.z = f2b(acc[m][n][2]); o.w = f2b(acc[m][n][3]);
        *(ushort4*)(VT + (c - 8192) * 2048 + rb) = o;
      } else {
#pragma unroll
        for (int j = 0; j < 4; ++j) Cq[(rb + j) * N + c] = f2b(acc[m][n][j]);
      }
    }
}

// ============ GEMM2: proven R2 structure (float out) ========================
__device__ __forceinline__ short8 frag_ld(const u16* base, int rbase, int fr, int fq) {
  const int r = rbase + fr;
  return *(const short8*)(base + r * 32 + ((fq ^ ((r >> 1) & 3)) << 3));
}

__global__ __launch_bounds__(512, 2) void gemm256(const u16* __restrict__ A,
                                                  const u16* __restrict__ B,
                                                  float* __restrict__ C,
                                                  int M, int N, int K) {
  __shared__ u16 lds[4 * 12288];          // 4 slots x (A 8192 + B 4096) u16
  const int tid = threadIdx.x;
  const int wid = tid >> 6, lane = tid & 63;
  const int fr = lane & 15, fq = lane >> 4;
  const int mA = (wid >> 1) * 64;
  const int nB = (wid & 1) * 64;

  const int nty = M >> 8;
  const int q = gridDim.x >> 3;
  const int wg = (blockIdx.x & 7) * q + (blockIdx.x >> 3);
  const int by = wg % nty;
  const int bx = wg / nty;
  const long row0 = (long)by * 256;
  const long col0 = (long)bx * 128;

  const int c0 = tid, c1 = 512 + tid, cB = tid;
  const int rA0 = c0 >> 2, j0 = (c0 & 3) ^ ((rA0 >> 1) & 3);
  const int rA1 = c1 >> 2, j1 = (c1 & 3) ^ ((rA1 >> 1) & 3);
  const int rB  = cB >> 2, j2 = (cB & 3) ^ ((rB >> 1) & 3);
  const u16* gA0 = A + (row0 + rA0) * (long)K + j0 * 8;
  const u16* gA1 = A + (row0 + rA1) * (long)K + j1 * 8;
  const u16* gB  = B + (col0 + rB) * (long)K + j2 * 8;
  const int dA0 = c0 * 8, dA1 = c1 * 8, dB = 8192 + cB * 8;

  f32x4 acc[4][4];
#pragma unroll
  for (int m = 0; m < 4; ++m)
#pragma unroll
    for (int n = 0; n < 4; ++n) acc[m][n] = f32x4{0.f, 0.f, 0.f, 0.f};

  const int NT = K >> 5;

#pragma unroll
  for (int pt = 0; pt < 3; ++pt) {
    u16* s = lds + pt * 12288;
    gload_lds16(gA0 + pt * 32, s + dA0);
    gload_lds16(gA1 + pt * 32, s + dA1);
    gload_lds16(gB  + pt * 32, s + dB);
  }
  wait_vmcnt<6>();
  __builtin_amdgcn_s_barrier();

  for (int t = 0; t < NT; ++t) {
    const u16* SA = lds + (t & 3) * 12288;
    const u16* SB = SA + 8192;
    u16* ST = lds + ((t + 3) & 3) * 12288;
    const bool st = (t + 3) < NT;
    const int sk = (t + 3) * 32;

    short8 a0 = frag_ld(SA, mA +  0, fr, fq);
    short8 a1 = frag_ld(SA, mA + 16, fr, fq);
    short8 b0 = frag_ld(SB, nB +  0, fr, fq);
    short8 b1 = frag_ld(SB, nB + 16, fr, fq);
    short8 b2 = frag_ld(SB, nB + 32, fr, fq);
    short8 b3 = frag_ld(SB, nB + 48, fr, fq);
    if (st) {
      gload_lds16(gA0 + sk, ST + dA0);
      gload_lds16(gA1 + sk, ST + dA1);
    }
    __builtin_amdgcn_s_barrier();
    __builtin_amdgcn_s_setprio(1);
    acc[0][0] = __builtin_amdgcn_mfma_f32_16x16x32_bf16(a0, b0, acc[0][0], 0, 0, 0);
    acc[0][1] = __builtin_amdgcn_mfma_f32_16x16x32_bf16(a0, b1, acc[0][1], 0, 0, 0);
    acc[0][2] = __builtin_amdgcn_mfma_f32_16x16x32_bf16(a0, b2, acc[0][2], 0, 0, 0);
    acc[0][3] = __builtin_amdgcn_mfma_f32_16x16x32_bf16(a0, b3, acc[0][3], 0, 0, 0);
    acc[1][0] = __builtin_amdgcn_mfma_f32_16x16x32_bf16(a1, b0, acc[1][0], 0, 0, 0);
    acc[1][1] = __builtin_amdgcn_mfma_f32_16x16x32_bf16(a1, b1, acc[1][1], 0, 0, 0);
    acc[1][2] = __builtin_amdgcn_mfma_f32_16x16x32_bf16(a1, b2, acc[1][2], 0, 0, 0);
    acc[1][3] = __builtin_amdgcn_mfma_f32_16x16x32_bf16(a1, b3, acc[1][3], 0, 0, 0);
    __builtin_amdgcn_s_setprio(0);
    __builtin_amdgcn_s_barrier();

    short8 a2 = frag_ld(SA, mA + 32, fr, fq);
    short8 a3 = frag_ld(SA, mA + 48, fr, fq);
    if (st) gload_lds16(gB + sk, ST + dB);
    __builtin_amdgcn_s_barrier();
    __builtin_amdgcn_s_setprio(1);
    acc[2][0] = __builtin_amdgcn_mfma_f32_16x16x32_bf16(a2, b0, acc[2][0], 0, 0, 0);
    acc[2][1] = __builtin_amdgcn_mfma_f32_16x16x32_bf16(a2, b1, acc[2][1], 0, 0, 0);
    acc[2][2] = __builtin_amdgcn_mfma_f32_16x16x32_bf16(a2, b2, acc[2][2], 0, 0, 0);
    acc[2][3] = __builtin_amdgcn_mfma_f32_16x16x32_bf16(a2, b3, acc[2][3], 0, 0, 0);
    acc[3][0] = __builtin_amdgcn_mfma_f32_16x16x32_bf16(a3, b0, acc[3][0], 0, 0, 0);
    acc[3][1] = __builtin_amdgcn_mfma_f32_16x16x32_bf16(a3, b1, acc[3][1], 0, 0, 0);
    acc[3][2] = __builtin_amdgcn_mfma_f32_16x16x32_bf16(a3, b2, acc[3][2], 0, 0, 0);
    acc[3][3] = __builtin_amdgcn_mfma_f32_16x16x32_bf16(a3, b3, acc[3][3], 0, 0, 0);
    __builtin_amdgcn_s_setprio(0);
    if (t + 3 < NT)      wait_vmcnt<6>();
    else if (t + 2 < NT) wait_vmcnt<3>();
    else                 wait_vmcnt<0>();
    __builtin_amdgcn_s_barrier();
  }

#pragma unroll
  for (int m = 0; m < 4; ++m)
#pragma unroll
    for (int n = 0; n < 4; ++n)
#pragma unroll
      for (int j = 0; j < 4; ++j) {
        const long r = row0 + mA + m * 16 + fq * 4 + j;
        const long c = col0 + nB + n * 16 + fr;
        C[r * N + c] = acc[m][n][j];
      }
}

// ---------------- RoPE on q,k (vectorized) ---------------------------------
__global__ __launch_bounds__(256) void rope_qk(u16* __restrict__ qkv,
                                               const float* __restrict__ cosb,
                                               const float* __restrict__ sinb) {
  const int idx = blockIdx.x * 256 + threadIdx.x;   // grid exact: 2,097,152
  const int dq  = idx & 15;
  const int h   = (idx >> 4) & 31;
  const int seg = (idx >> 9) & 1;                   // 0 = q, 1 = k
  const int s   = idx >> 10;
  const int d0  = dq * 4;
  u16* base = qkv + (long)s * 12288 + seg * 4096 + h * 128;
  const ushort4 x1 = *(const ushort4*)(base + d0);
  const ushort4 x2 = *(const ushort4*)(base + d0 + 64);
  const float4 c1 = *(const float4*)(cosb + s * 128 + d0);
  const float4 s1 = *(const float4*)(sinb + s * 128 + d0);
  const float4 c2 = *(const float4*)(cosb + s * 128 + d0 + 64);
  const float4 s2 = *(const float4*)(sinb + s * 128 + d0 + 64);
  const float scale = seg ? 1.0f : 0.08838834764831845f;   // 1/sqrt(128) on q
  float x1f[4] = {b2f(x1.x), b2f(x1.y), b2f(x1.z), b2f(x1.w)};
  float x2f[4] = {b2f(x2.x), b2f(x2.y), b2f(x2.z), b2f(x2.w)};
  const float c1a[4] = {c1.x, c1.y, c1.z, c1.w}, s1a[4] = {s1.x, s1.y, s1.z, s1.w};
  const float c2a[4] = {c2.x, c2.y, c2.z, c2.w}, s2a[4] = {s2.x, s2.y, s2.z, s2.w};
  ushort4 o1, o2;
  u16* o1p = (u16*)&o1; u16* o2p = (u16*)&o2;
#pragma unroll
  for (int j = 0; j < 4; ++j) {
    o1p[j] = f2b((x1f[j] * c1a[j] - x2f[j] * s1a[j]) * scale);
    o2p[j] = f2b((x2f[j] * c2a[j] + x1f[j] * s2a[j]) * scale);
  }
  *(ushort4*)(base + d0) = o1;
  *(ushort4*)(base + d0 + 64) = o2;
}

// ---------------- causal flash attention ------------------------------------
__global__ __launch_bounds__(256) void attn_fwd(const u16* __restrict__ Qb,
                                                const u16* __restrict__ Kb,
                                                const u16* __restrict__ Vt,
                                                u16* __restrict__ Ob) {
  const int h  = blockIdx.y;
  const int bxr = gridDim.x - 1 - blockIdx.x;   // longest blocks dispatch first
  const int q0 = bxr * 64;
  const int tid = threadIdx.x;
  const int wid = tid >> 6, lane = tid & 63;
  const int fr = lane & 15, fq = lane >> 4;

  __shared__ u16 Ks[64 * 128];
  __shared__ u16 Vts[128 * 64];
  __shared__ u16 Ps[4][16 * 72];

  short8 qf[4];
  {
    const long qrow = q0 + wid * 16 + fr;
#pragma unroll
    for (int kk = 0; kk < 4; ++kk)
      qf[kk] = *(const short8*)(Qb + qrow * 12288 + h * 128 + kk * 32 + fq * 8);
  }

  f32x4 Oacc[8];
#pragma unroll
  for (int f = 0; f < 8; ++f) Oacc[f] = f32x4{0.f, 0.f, 0.f, 0.f};
  float mrun[4], lrun[4];
#pragma unroll
  for (int j = 0; j < 4; ++j) { mrun[j] = -1e30f; lrun[j] = 0.f; }

  const int nt = bxr + 1;
  for (int t = 0; t < nt; ++t) {
    const int kv0 = t * 64;
#pragma unroll
    for (int i = 0; i < 4; ++i) {
      const int c = wid * 4 + i;
      {
        const int r = c * 4 + (lane >> 4);
        const int p = lane & 15;
        const int jsrc = p ^ (r & 7);
        gload_lds16(Kb + (long)(kv0 + r) * 12288 + h * 128 + jsrc * 8,
                    (char*)Ks + c * 1024);
      }
      {
        const int d = c * 8 + (lane >> 3);
        const int p = lane & 7;
        const int jsrc = p ^ (d & 7);
        gload_lds16(Vt + (long)(h * 128 + d) * 2048 + kv0 + jsrc * 8,
                    (char*)Vts + c * 1024);
      }
    }
    __syncthreads();

    f32x4 S[4];
#pragma unroll
    for (int n = 0; n < 4; ++n) S[n] = f32x4{0.f, 0.f, 0.f, 0.f};
#pragma unroll
    for (int kk = 0; kk < 4; ++kk) {
#pragma unroll
      for (int n = 0; n < 4; ++n) {
        const int r = n * 16 + fr;
        const int p = (kk * 4 + fq) ^ (r & 7);
        short8 kf = *(const short8*)((const char*)Ks + r * 256 + p * 16);
        S[n] = __builtin_amdgcn_mfma_f32_16x16x32_bf16(qf[kk], kf, S[n], 0, 0, 0);
      }
    }

    float P[4][4];
    float tm[4] = {-1e30f, -1e30f, -1e30f, -1e30f};
#pragma unroll
    for (int n = 0; n < 4; ++n) {
      const int kv = kv0 + n * 16 + fr;
#pragma unroll
      for (int j = 0; j < 4; ++j) {
        const int qi = q0 + wid * 16 + fq * 4 + j;
        const float s = (kv <= qi) ? S[n][j] : -1e30f;
        P[n][j] = s;
        tm[j] = fmaxf(tm[j], s);
      }
    }
#pragma unroll
    for (int j = 0; j < 4; ++j)
#pragma unroll
      for (int msk = 1; msk < 16; msk <<= 1)
        tm[j] = fmaxf(tm[j], __shfl_xor(tm[j], msk));

    float al[4], rs[4];
#pragma unroll
    for (int j = 0; j < 4; ++j) {
      const float mn = fmaxf(mrun[j], tm[j]);
      al[j] = __expf(mrun[j] - mn);
      mrun[j] = mn;
      rs[j] = 0.f;
    }
#pragma unroll
    for (int n = 0; n < 4; ++n)
#pragma unroll
      for (int j = 0; j < 4; ++j) {
        const float p = __expf(P[n][j] - mrun[j]);
        P[n][j] = p;
        rs[j] += p;
      }
#pragma unroll
    for (int j = 0; j < 4; ++j) {
#pragma unroll
      for (int msk = 1; msk < 16; msk <<= 1) rs[j] += __shfl_xor(rs[j], msk);
      lrun[j] = lrun[j] * al[j] + rs[j];
    }
#pragma unroll
    for (int f = 0; f < 8; ++f) {
      f32x4 o = Oacc[f];
#pragma unroll
      for (int j = 0; j < 4; ++j) o[j] *= al[j];
      Oacc[f] = o;
    }

#pragma unroll
    for (int n = 0; n < 4; ++n)
#pragma unroll
      for (int j = 0; j < 4; ++j)
        Ps[wid][(fq * 4 + j) * 72 + n * 16 + fr] = f2b(P[n][j]);

#pragma unroll
    for (int kb = 0; kb < 2; ++kb) {
      short8 pa = *(const short8*)(Ps[wid] + fr * 72 + kb * 32 + fq * 8);
#pragma unroll
      for (int f = 0; f < 8; ++f) {
        const int d = f * 16 + fr;
        const int p = (kb * 4 + fq) ^ (d & 7);
        short8 vf = *(const short8*)((const char*)Vts + d * 128 + p * 16);
        Oacc[f] = __builtin_amdgcn_mfma_f32_16x16x32_bf16(pa, vf, Oacc[f], 0, 0, 0);
      }
    }
    __syncthreads();
  }

#pragma unroll
  for (int j = 0; j < 4; ++j) {
    const float inv = 1.f / lrun[j];
    const long r = q0 + wid * 16 + fq * 4 + j;
#pragma unroll
    for (int f = 0; f < 8; ++f)
      Ob[r * 4096 + h * 128 + f * 16 + fr] = f2b(Oacc[f][j] * inv);
  }
}

// ---------------- launch ----------------------------------------------------
extern "C" void kernel_launch(void* const* d_in, const int* in_sizes, int n_in,
                              void* d_out, int out_size, void* d_ws, size_t ws_size,
                              hipStream_t stream) {
  const float* hs   = (const float*)d_in[0];   // (2048, 4096)
  const float* cosb = (const float*)d_in[1];   // (2048, 128)
  const float* sinb = (const float*)d_in[2];   // (2048, 128)
  const float* wp   = (const float*)d_in[3];   // (12288, 4096)
  const float* wo   = (const float*)d_in[4];   // (4096, 4096)
  float* out = (float*)d_out;                  // (2048, 4096)
  char* ws = (char*)d_ws;

  // workspace (180 MB peak):
  //   [0,16M)    h_bf   -> reused by attn output after GEMM1
  //   [16M,116M) wp_bf  -> reused by wo_bf after GEMM1
  //   [116M,164M) qkv (q,k written; v region unused)
  //   [164M,180M) vt (4096 x 2048, written by GEMM1 epilogue)
  u16* h_bf  = (u16*)(ws);
  u16* attn  = (u16*)(ws);
  u16* wp_bf = (u16*)(ws + 16777216);
  u16* wo_bf = (u16*)(ws + 16777216);
  u16* qkv   = (u16*)(ws + 121634816);
  u16* vt    = (u16*)(ws + 171966464);

  cvt_hp<<<4096, 256, 0, stream>>>(hs, wp, h_bf, wp_bf);
  gemm8p<<<512, 512, 0, stream>>>(h_bf, wp_bf, qkv, vt, 2048, 12288, 4096);
  cvt_bf16<<<2048, 256, 0, stream>>>(wo, wo_bf, 4194304);
  rope_qk<<<8192, 256, 0, stream>>>(qkv, cosb, sinb);
  attn_fwd<<<dim3(32, 32), 256, 0, stream>>>(qkv, qkv + 4096, vt, attn);
  gemm256<<<256, 512, 0, stream>>>(attn, wo_bf, out, 2048, 4096, 4096);
}

// Round 8
// 507.664 us; speedup vs baseline: 1.4891x; 1.0022x over previous
//
#include <hip/hip_runtime.h>

typedef unsigned short u16;
typedef unsigned int   u32;
typedef __attribute__((ext_vector_type(8))) short short8;   // 8 x bf16
typedef __attribute__((ext_vector_type(4))) float f32x4;

__device__ __forceinline__ float b2f(u16 u) {
  union { float f; u32 i; } v; v.i = ((u32)u) << 16; return v.f;
}
__device__ __forceinline__ u16 f2b(float f) {
  union { float f; u32 i; } v; v.f = f;
  u32 r = v.i + 0x7fffu + ((v.i >> 16) & 1u);   // RNE
  return (u16)(r >> 16);
}

__device__ __forceinline__ void gload_lds16(const void* g, void* l) {
  __builtin_amdgcn_global_load_lds(
      (const __attribute__((address_space(1))) void*)g,
      (__attribute__((address_space(3))) void*)l, 16, 0, 0);
}

template <int N> __device__ __forceinline__ void wait_vmcnt() {
  if constexpr (N == 0)      asm volatile("s_waitcnt vmcnt(0)" ::: "memory");
  else if constexpr (N == 2) asm volatile("s_waitcnt vmcnt(2)" ::: "memory");
  else if constexpr (N == 3) asm volatile("s_waitcnt vmcnt(3)" ::: "memory");
  else if constexpr (N == 6) asm volatile("s_waitcnt vmcnt(6)" ::: "memory");
  else static_assert(N < 0, "unsupported vmcnt literal");
}

// ---------------- f32 -> bf16 converts ----------------
__device__ __forceinline__ ushort4 cvt4(float4 v) {
  ushort4 o;
  o.x = f2b(v.x); o.y = f2b(v.y); o.z = f2b(v.z); o.w = f2b(v.w);
  return o;
}

__global__ __launch_bounds__(256) void cvt_hp(const float* __restrict__ hs,
                                              const float* __restrict__ wp,
                                              u16* __restrict__ h_bf,
                                              u16* __restrict__ wp_bf) {
  const long H4 = 2097152, W4 = 12582912;   // float4 counts
  for (long i = (long)blockIdx.x * 256 + threadIdx.x; i < H4 + W4;
       i += (long)gridDim.x * 256) {
    if (i < H4)
      ((ushort4*)h_bf)[i] = cvt4(((const float4*)hs)[i]);
    else
      ((ushort4*)wp_bf)[i - H4] = cvt4(((const float4*)wp)[i - H4]);
  }
}

__global__ __launch_bounds__(256) void cvt_bf16(const float* __restrict__ in,
                                                u16* __restrict__ out, int n4) {
  for (long i = (long)blockIdx.x * 256 + threadIdx.x; i < n4; i += (long)gridDim.x * 256)
    ((ushort4*)out)[i] = cvt4(((const float4*)in)[i]);
}

__device__ __forceinline__ short8 frag_ld64(const u16* base, int rbase, int kk,
                                            int fr, int fq) {
  const int r = rbase + fr;
  return *(const short8*)(base + r * 64 + ((((kk << 2) + fq) ^ (r & 7)) << 3));
}

// ============ GEMM1: 4-phase, tile 256x192 (proven R7, unchanged) ==========
__global__ __launch_bounds__(512, 2) void gemm8p(const u16* __restrict__ A,
                                                 const u16* __restrict__ B,
                                                 u16* __restrict__ Cq,
                                                 u16* __restrict__ VT,
                                                 int M, int N, int K) {
  constexpr int AE = 16384;                 // A region u16 (256x64)
  constexpr int BUFSZ = AE + 12288;         // + B region (192x64) = 28672 u16
  __shared__ u16 lds[2 * BUFSZ];            // 114,688 B
  const int tid = threadIdx.x;
  const int wid = tid >> 6, lane = tid & 63;
  const int fr = lane & 15, fq = lane >> 4;
  const int mA = (wid >> 2) * 128;          // wm in {0,1}
  const int nB = (wid & 3) * 48;            // wn in {0..3}

  const int nty = M >> 8;                   // 8
  const int qx = gridDim.x >> 3;
  const int wg = (blockIdx.x & 7) * qx + (blockIdx.x >> 3);
  const int by = wg % nty, bx = wg / nty;
  const long row0 = (long)by * 256, col0 = (long)bx * 192;

  const int rr8 = tid >> 3;
  const int jl = (tid & 7) ^ (rr8 & 7);
  const u16* gA = A + (row0 + rr8) * (long)K + jl * 8;
  const u16* gB = B + (col0 + rr8) * (long)K + jl * 8;

  f32x4 acc[8][3];
#pragma unroll
  for (int m = 0; m < 8; ++m)
#pragma unroll
    for (int n = 0; n < 3; ++n) acc[m][n] = f32x4{0.f, 0.f, 0.f, 0.f};

  const int NT = K >> 6;                    // BK = 64

  auto stageA = [&](int i, int t) {
    gload_lds16(gA + (long)(i * 64) * K + (long)t * 64,
                lds + (t & 1) * BUFSZ + (i * 512 + tid) * 8);
  };
  auto stageB = [&](int i, int t) {
    gload_lds16(gB + (long)(i * 64) * K + (long)t * 64,
                lds + (t & 1) * BUFSZ + AE + (i * 512 + tid) * 8);
  };

#pragma unroll
  for (int i = 0; i < 4; ++i) stageA(i, 0);
#pragma unroll
  for (int i = 0; i < 3; ++i) stageB(i, 0);
#pragma unroll
  for (int i = 0; i < 3; ++i) stageB(i, 1);
  wait_vmcnt<3>();
  __builtin_amdgcn_s_barrier();

  for (int t = 0; t < NT; ++t) {
    const u16* SA = lds + (t & 1) * BUFSZ;
    const u16* SB = SA + AE;
    short8 a0[4], a1[4], b0[3], b1[3];

    // ---- phase 1: (qm0,kk0); all B frags; stage A i=0,1 ----
#pragma unroll
    for (int m = 0; m < 4; ++m) a0[m] = frag_ld64(SA, mA + m * 16, 0, fr, fq);
#pragma unroll
    for (int n = 0; n < 3; ++n) b0[n] = frag_ld64(SB, nB + n * 16, 0, fr, fq);
#pragma unroll
    for (int n = 0; n < 3; ++n) b1[n] = frag_ld64(SB, nB + n * 16, 1, fr, fq);
    if (t + 1 < NT) { stageA(0, t + 1); stageA(1, t + 1); }
    __builtin_amdgcn_s_setprio(1);
#pragma unroll
    for (int m = 0; m < 4; ++m)
#pragma unroll
      for (int n = 0; n < 3; ++n)
        acc[m][n] = __builtin_amdgcn_mfma_f32_16x16x32_bf16(a0[m], b0[n], acc[m][n], 0, 0, 0);
    __builtin_amdgcn_s_setprio(0);
    asm volatile("s_waitcnt lgkmcnt(0)" ::: "memory");   // all B(t) reads retired
    __builtin_amdgcn_s_barrier();

    // ---- phase 2: (qm1,kk0); stage A i=2,3 ----
#pragma unroll
    for (int m = 0; m < 4; ++m) a1[m] = frag_ld64(SA, mA + 64 + m * 16, 0, fr, fq);
    if (t + 1 < NT) { stageA(2, t + 1); stageA(3, t + 1); }
    __builtin_amdgcn_s_setprio(1);
#pragma unroll
    for (int m = 0; m < 4; ++m)
#pragma unroll
      for (int n = 0; n < 3; ++n)
        acc[4 + m][n] = __builtin_amdgcn_mfma_f32_16x16x32_bf16(a1[m], b0[n], acc[4 + m][n], 0, 0, 0);
    __builtin_amdgcn_s_setprio(0);
    __builtin_amdgcn_s_barrier();

    // ---- phase 3: (qm0,kk1); stage B i=0,1 into buf(t) B-region ----
#pragma unroll
    for (int m = 0; m < 4; ++m) a0[m] = frag_ld64(SA, mA + m * 16, 1, fr, fq);
    if (t + 2 < NT) { stageB(0, t + 2); stageB(1, t + 2); }
    __builtin_amdgcn_s_setprio(1);
#pragma unroll
    for (int m = 0; m < 4; ++m)
#pragma unroll
      for (int n = 0; n < 3; ++n)
        acc[m][n] = __builtin_amdgcn_mfma_f32_16x16x32_bf16(a0[m], b1[n], acc[m][n], 0, 0, 0);
    __builtin_amdgcn_s_setprio(0);
    __builtin_amdgcn_s_barrier();

    // ---- phase 4: (qm1,kk1); stage B i=2; counted vmcnt ----
#pragma unroll
    for (int m = 0; m < 4; ++m) a1[m] = frag_ld64(SA, mA + 64 + m * 16, 1, fr, fq);
    if (t + 2 < NT) stageB(2, t + 2);
    __builtin_amdgcn_s_setprio(1);
#pragma unroll
    for (int m = 0; m < 4; ++m)
#pragma unroll
      for (int n = 0; n < 3; ++n)
        acc[4 + m][n] = __builtin_amdgcn_mfma_f32_16x16x32_bf16(a1[m], b1[n], acc[4 + m][n], 0, 0, 0);
    __builtin_amdgcn_s_setprio(0);
    if (t + 2 < NT) wait_vmcnt<3>();
    else            wait_vmcnt<0>();
    __builtin_amdgcn_s_barrier();
  }

#pragma unroll
  for (int m = 0; m < 8; ++m)
#pragma unroll
    for (int n = 0; n < 3; ++n) {
      const long c = col0 + nB + n * 16 + fr;
      const long rb = row0 + mA + m * 16 + fq * 4;
      if (c >= 8192) {
        ushort4 o;
        o.x = f2b(acc[m][n][0]); o.y = f2b(acc[m][n][1]);
        o.z = f2b(acc[m][n][2]); o.w = f2b(acc[m][n][3]);
        *(ushort4*)(VT + (c - 8192) * 2048 + rb) = o;
      } else {
#pragma unroll
        for (int j = 0; j < 4; ++j) Cq[(rb + j) * N + c] = f2b(acc[m][n][j]);
      }
    }
}

// ============ GEMM2: 4-phase, tile 256x128 (same schedule shape) ============
// 8 waves 2M x 4N, per-wave 128x32. LDS 2 x 48 KiB. grid 8x32 = 256 = 1/CU.
// ph1: a(qm0,kk0) + ALL 8 B frags; stage A h0,h1(t+1); 8 MFMA; lgkm(0); barrier
// ph2: a(qm1,kk0); stage A h2,h3(t+1); 8 MFMA; barrier
// ph3: a(qm0,kk1); stage B h0(t+2) -> buf(t) B-region (free after ph1); barrier
// ph4: a(qm1,kk1); stage B h1(t+2); vmcnt(2); barrier
__global__ __launch_bounds__(512, 2) void gemm2_4p(const u16* __restrict__ A,
                                                   const u16* __restrict__ B,
                                                   float* __restrict__ C,
                                                   int M, int N, int K) {
  constexpr int AE = 16384;                 // A region u16 (256x64)
  constexpr int BUFSZ = AE + 8192;          // + B region (128x64) = 24576 u16
  __shared__ u16 lds[2 * BUFSZ];            // 98,304 B
  const int tid = threadIdx.x;
  const int wid = tid >> 6, lane = tid & 63;
  const int fr = lane & 15, fq = lane >> 4;
  const int mA = (wid >> 2) * 128;          // wm in {0,1}
  const int nB = (wid & 3) * 32;            // wn in {0..3}

  const int nty = M >> 8;                   // 8
  const int qx = gridDim.x >> 3;
  const int wg = (blockIdx.x & 7) * qx + (blockIdx.x >> 3);
  const int by = wg % nty, bx = wg / nty;
  const long row0 = (long)by * 256, col0 = (long)bx * 128;

  const int rr8 = tid >> 3;
  const int jl = (tid & 7) ^ (rr8 & 7);
  const u16* gA = A + (row0 + rr8) * (long)K + jl * 8;
  const u16* gB = B + (col0 + rr8) * (long)K + jl * 8;

  f32x4 acc[8][2];
#pragma unroll
  for (int m = 0; m < 8; ++m)
#pragma unroll
    for (int n = 0; n < 2; ++n) acc[m][n] = f32x4{0.f, 0.f, 0.f, 0.f};

  const int NT = K >> 6;

  auto stageA = [&](int i, int t) {
    gload_lds16(gA + (long)(i * 64) * K + (long)t * 64,
                lds + (t & 1) * BUFSZ + (i * 512 + tid) * 8);
  };
  auto stageB = [&](int i, int t) {
    gload_lds16(gB + (long)(i * 64) * K + (long)t * 64,
                lds + (t & 1) * BUFSZ + AE + (i * 512 + tid) * 8);
  };

#pragma unroll
  for (int i = 0; i < 4; ++i) stageA(i, 0);
#pragma unroll
  for (int i = 0; i < 2; ++i) stageB(i, 0);
#pragma unroll
  for (int i = 0; i < 2; ++i) stageB(i, 1);
  wait_vmcnt<2>();
  __builtin_amdgcn_s_barrier();

  for (int t = 0; t < NT; ++t) {
    const u16* SA = lds + (t & 1) * BUFSZ;
    const u16* SB = SA + AE;
    short8 a0[4], a1[4], b0[2], b1[2];

    // ---- phase 1 ----
#pragma unroll
    for (int m = 0; m < 4; ++m) a0[m] = frag_ld64(SA, mA + m * 16, 0, fr, fq);
#pragma unroll
    for (int n = 0; n < 2; ++n) b0[n] = frag_ld64(SB, nB + n * 16, 0, fr, fq);
#pragma unroll
    for (int n = 0; n < 2; ++n) b1[n] = frag_ld64(SB, nB + n * 16, 1, fr, fq);
    if (t + 1 < NT) { stageA(0, t + 1); stageA(1, t + 1); }
    __builtin_amdgcn_s_setprio(1);
#pragma unroll
    for (int m = 0; m < 4; ++m)
#pragma unroll
      for (int n = 0; n < 2; ++n)
        acc[m][n] = __builtin_amdgcn_mfma_f32_16x16x32_bf16(a0[m], b0[n], acc[m][n], 0, 0, 0);
    __builtin_amdgcn_s_setprio(0);
    asm volatile("s_waitcnt lgkmcnt(0)" ::: "memory");   // all B(t) reads retired
    __builtin_amdgcn_s_barrier();

    // ---- phase 2 ----
#pragma unroll
    for (int m = 0; m < 4; ++m) a1[m] = frag_ld64(SA, mA + 64 + m * 16, 0, fr, fq);
    if (t + 1 < NT) { stageA(2, t + 1); stageA(3, t + 1); }
    __builtin_amdgcn_s_setprio(1);
#pragma unroll
    for (int m = 0; m < 4; ++m)
#pragma unroll
      for (int n = 0; n < 2; ++n)
        acc[4 + m][n] = __builtin_amdgcn_mfma_f32_16x16x32_bf16(a1[m], b0[n], acc[4 + m][n], 0, 0, 0);
    __builtin_amdgcn_s_setprio(0);
    __builtin_amdgcn_s_barrier();

    // ---- phase 3 ----
#pragma unroll
    for (int m = 0; m < 4; ++m) a0[m] = frag_ld64(SA, mA + m * 16, 1, fr, fq);
    if (t + 2 < NT) stageB(0, t + 2);
    __builtin_amdgcn_s_setprio(1);
#pragma unroll
    for (int m = 0; m < 4; ++m)
#pragma unroll
      for (int n = 0; n < 2; ++n)
        acc[m][n] = __builtin_amdgcn_mfma_f32_16x16x32_bf16(a0[m], b1[n], acc[m][n], 0, 0, 0);
    __builtin_amdgcn_s_setprio(0);
    __builtin_amdgcn_s_barrier();

    // ---- phase 4 ----
#pragma unroll
    for (int m = 0; m < 4; ++m) a1[m] = frag_ld64(SA, mA + 64 + m * 16, 1, fr, fq);
    if (t + 2 < NT) stageB(1, t + 2);
    __builtin_amdgcn_s_setprio(1);
#pragma unroll
    for (int m = 0; m < 4; ++m)
#pragma unroll
      for (int n = 0; n < 2; ++n)
        acc[4 + m][n] = __builtin_amdgcn_mfma_f32_16x16x32_bf16(a1[m], b1[n], acc[4 + m][n], 0, 0, 0);
    __builtin_amdgcn_s_setprio(0);
    if (t + 2 < NT) wait_vmcnt<2>();
    else            wait_vmcnt<0>();
    __builtin_amdgcn_s_barrier();
  }

#pragma unroll
  for (int m = 0; m < 8; ++m)
#pragma unroll
    for (int n = 0; n < 2; ++n)
#pragma unroll
      for (int j = 0; j < 4; ++j) {
        const long r = row0 + mA + m * 16 + fq * 4 + j;
        const long c = col0 + nB + n * 16 + fr;
        C[r * N + c] = acc[m][n][j];
      }
}

// ---------------- RoPE on q,k (vectorized) ---------------------------------
__global__ __launch_bounds__(256) void rope_qk(u16* __restrict__ qkv,
                                               const float* __restrict__ cosb,
                                               const float* __restrict__ sinb) {
  const int idx = blockIdx.x * 256 + threadIdx.x;   // grid exact: 2,097,152
  const int dq  = idx & 15;
  const int h   = (idx >> 4) & 31;
  const int seg = (idx >> 9) & 1;                   // 0 = q, 1 = k
  const int s   = idx >> 10;
  const int d0  = dq * 4;
  u16* base = qkv + (long)s * 12288 + seg * 4096 + h * 128;
  const ushort4 x1 = *(const ushort4*)(base + d0);
  const ushort4 x2 = *(const ushort4*)(base + d0 + 64);
  const float4 c1 = *(const float4*)(cosb + s * 128 + d0);
  const float4 s1 = *(const float4*)(sinb + s * 128 + d0);
  const float4 c2 = *(const float4*)(cosb + s * 128 + d0 + 64);
  const float4 s2 = *(const float4*)(sinb + s * 128 + d0 + 64);
  const float scale = seg ? 1.0f : 0.08838834764831845f;   // 1/sqrt(128) on q
  float x1f[4] = {b2f(x1.x), b2f(x1.y), b2f(x1.z), b2f(x1.w)};
  float x2f[4] = {b2f(x2.x), b2f(x2.y), b2f(x2.z), b2f(x2.w)};
  const float c1a[4] = {c1.x, c1.y, c1.z, c1.w}, s1a[4] = {s1.x, s1.y, s1.z, s1.w};
  const float c2a[4] = {c2.x, c2.y, c2.z, c2.w}, s2a[4] = {s2.x, s2.y, s2.z, s2.w};
  ushort4 o1, o2;
  u16* o1p = (u16*)&o1; u16* o2p = (u16*)&o2;
#pragma unroll
  for (int j = 0; j < 4; ++j) {
    o1p[j] = f2b((x1f[j] * c1a[j] - x2f[j] * s1a[j]) * scale);
    o2p[j] = f2b((x2f[j] * c2a[j] + x1f[j] * s2a[j]) * scale);
  }
  *(ushort4*)(base + d0) = o1;
  *(ushort4*)(base + d0 + 64) = o2;
}

// ---------------- causal flash attention (double-buffered K/V) --------------
__global__ __launch_bounds__(256) void attn_fwd(const u16* __restrict__ Qb,
                                                const u16* __restrict__ Kb,
                                                const u16* __restrict__ Vt,
                                                u16* __restrict__ Ob) {
  const int h  = blockIdx.y;
  const int bxr = gridDim.x - 1 - blockIdx.x;   // longest blocks dispatch first
  const int q0 = bxr * 64;
  const int tid = threadIdx.x;
  const int wid = tid >> 6, lane = tid & 63;
  const int fr = lane & 15, fq = lane >> 4;

  __shared__ u16 Ks[2][64 * 128];    // 2 x 16 KB
  __shared__ u16 Vts[2][128 * 64];   // 2 x 16 KB
  __shared__ u16 Ps[4][16 * 72];     // 9216 B

  auto stage = [&](int t, int buf) {
    const int kv0 = t * 64;
#pragma unroll
    for (int i = 0; i < 4; ++i) {
      const int c = wid * 4 + i;
      {
        const int r = c * 4 + (lane >> 4);
        const int p = lane & 15;
        const int jsrc = p ^ (r & 7);
        gload_lds16(Kb + (long)(kv0 + r) * 12288 + h * 128 + jsrc * 8,
                    (char*)Ks[buf] + c * 1024);
      }
      {
        const int d = c * 8 + (lane >> 3);
        const int p = lane & 7;
        const int jsrc = p ^ (d & 7);
        gload_lds16(Vt + (long)(h * 128 + d) * 2048 + kv0 + jsrc * 8,
                    (char*)Vts[buf] + c * 1024);
      }
    }
  };

  short8 qf[4];
  {
    const long qrow = q0 + wid * 16 + fr;
#pragma unroll
    for (int kk = 0; kk < 4; ++kk)
      qf[kk] = *(const short8*)(Qb + qrow * 12288 + h * 128 + kk * 32 + fq * 8);
  }

  f32x4 Oacc[8];
#pragma unroll
  for (int f = 0; f < 8; ++f) Oacc[f] = f32x4{0.f, 0.f, 0.f, 0.f};
  float mrun[4], lrun[4];
#pragma unroll
  for (int j = 0; j < 4; ++j) { mrun[j] = -1e30f; lrun[j] = 0.f; }

  const int nt = bxr + 1;
  stage(0, 0);
  asm volatile("s_waitcnt vmcnt(0)" ::: "memory");
  __builtin_amdgcn_s_barrier();

  for (int t = 0; t < nt; ++t) {
    const int cur = t & 1;
    const int kv0 = t * 64;
    if (t + 1 < nt) stage(t + 1, cur ^ 1);

    f32x4 S[4];
#pragma unroll
    for (int n = 0; n < 4; ++n) S[n] = f32x4{0.f, 0.f, 0.f, 0.f};
#pragma unroll
    for (int kk = 0; kk < 4; ++kk) {
#pragma unroll
      for (int n = 0; n < 4; ++n) {
        const int r = n * 16 + fr;
        const int p = (kk * 4 + fq) ^ (r & 7);
        short8 kf = *(const short8*)((const char*)Ks[cur] + r * 256 + p * 16);
        S[n] = __builtin_amdgcn_mfma_f32_16x16x32_bf16(qf[kk], kf, S[n], 0, 0, 0);
      }
    }

    float P[4][4];
    float tm[4] = {-1e30f, -1e30f, -1e30f, -1e30f};
#pragma unroll
    for (int n = 0; n < 4; ++n) {
      const int kv = kv0 + n * 16 + fr;
#pragma unroll
      for (int j = 0; j < 4; ++j) {
        const int qi = q0 + wid * 16 + fq * 4 + j;
        const float s = (kv <= qi) ? S[n][j] : -1e30f;
        P[n][j] = s;
        tm[j] = fmaxf(tm[j], s);
      }
    }
#pragma unroll
    for (int j = 0; j < 4; ++j)
#pragma unroll
      for (int msk = 1; msk < 16; msk <<= 1)
        tm[j] = fmaxf(tm[j], __shfl_xor(tm[j], msk));

    float al[4], rs[4];
#pragma unroll
    for (int j = 0; j < 4; ++j) {
      const float mn = fmaxf(mrun[j], tm[j]);
      al[j] = __expf(mrun[j] - mn);
      mrun[j] = mn;
      rs[j] = 0.f;
    }
#pragma unroll
    for (int n = 0; n < 4; ++n)
#pragma unroll
      for (int j = 0; j < 4; ++j) {
        const float p = __expf(P[n][j] - mrun[j]);
        P[n][j] = p;
        rs[j] += p;
      }
#pragma unroll
    for (int j = 0; j < 4; ++j) {
#pragma unroll
      for (int msk = 1; msk < 16; msk <<= 1) rs[j] += __shfl_xor(rs[j], msk);
      lrun[j] = lrun[j] * al[j] + rs[j];
    }
#pragma unroll
    for (int f = 0; f < 8; ++f) {
      f32x4 o = Oacc[f];
#pragma unroll
      for (int j = 0; j < 4; ++j) o[j] *= al[j];
      Oacc[f] = o;
    }

#pragma unroll
    for (int n = 0; n < 4; ++n)
#pragma unroll
      for (int j = 0; j < 4; ++j)
        Ps[wid][(fq * 4 + j) * 72 + n * 16 + fr] = f2b(P[n][j]);

#pragma unroll
    for (int kb = 0; kb < 2; ++kb) {
      short8 pa = *(const short8*)(Ps[wid] + fr * 72 + kb * 32 + fq * 8);
#pragma unroll
      for (int f = 0; f < 8; ++f) {
        const int d = f * 16 + fr;
        const int p = (kb * 4 + fq) ^ (d & 7);
        short8 vf = *(const short8*)((const char*)Vts[cur] + d * 128 + p * 16);
        Oacc[f] = __builtin_amdgcn_mfma_f32_16x16x32_bf16(pa, vf, Oacc[f], 0, 0, 0);
      }
    }
    // stage(t+1) landed (issued at iter start, covered by this tile's compute)
    asm volatile("s_waitcnt vmcnt(0)" ::: "memory");
    __builtin_amdgcn_s_barrier();
  }

#pragma unroll
  for (int j = 0; j < 4; ++j) {
    const float inv = 1.f / lrun[j];
    const long r = q0 + wid * 16 + fq * 4 + j;
#pragma unroll
    for (int f = 0; f < 8; ++f)
      Ob[r * 4096 + h * 128 + f * 16 + fr] = f2b(Oacc[f][j] * inv);
  }
}

// ---------------- launch ----------------------------------------------------
extern "C" void kernel_launch(void* const* d_in, const int* in_sizes, int n_in,
                              void* d_out, int out_size, void* d_ws, size_t ws_size,
                              hipStream_t stream) {
  const float* hs   = (const float*)d_in[0];   // (2048, 4096)
  const float* cosb = (const float*)d_in[1];   // (2048, 128)
  const float* sinb = (const float*)d_in[2];   // (2048, 128)
  const float* wp   = (const float*)d_in[3];   // (12288, 4096)
  const float* wo   = (const float*)d_in[4];   // (4096, 4096)
  float* out = (float*)d_out;                  // (2048, 4096)
  char* ws = (char*)d_ws;

  // workspace (180 MB peak):
  //   [0,16M)    h_bf   -> reused by attn output after GEMM1
  //   [16M,116M) wp_bf  -> reused by wo_bf after GEMM1
  //   [116M,164M) qkv (q,k written; v region unused)
  //   [164M,180M) vt (4096 x 2048, written by GEMM1 epilogue)
  u16* h_bf  = (u16*)(ws);
  u16* attn  = (u16*)(ws);
  u16* wp_bf = (u16*)(ws + 16777216);
  u16* wo_bf = (u16*)(ws + 16777216);
  u16* qkv   = (u16*)(ws + 121634816);
  u16* vt    = (u16*)(ws + 171966464);

  cvt_hp<<<4096, 256, 0, stream>>>(hs, wp, h_bf, wp_bf);
  gemm8p<<<512, 512, 0, stream>>>(h_bf, wp_bf, qkv, vt, 2048, 12288, 4096);
  cvt_bf16<<<2048, 256, 0, stream>>>(wo, wo_bf, 4194304);
  rope_qk<<<8192, 256, 0, stream>>>(qkv, cosb, sinb);
  attn_fwd<<<dim3(32, 32), 256, 0, stream>>>(qkv, qkv + 4096, vt, attn);
  gemm2_4p<<<256, 512, 0, stream>>>(attn, wo_bf, out, 2048, 4096, 4096);
}